// Round 1
// baseline (1372.822 us; speedup 1.0000x reference)
//
#include <hip/hip_runtime.h>
#include <hip/hip_bf16.h>

// Problem constants (fixed by setup_inputs)
#define NG      100
#define NPG     500
#define EPG     4000
#define HID     128
#define NNODES  (NG*NPG)     // 50000
#define NE      (NG*EPG)     // 400000
#define KSEL    2000         // ceil(0.5*4000)
#define NB_SCAN ((NNODES + 255) / 256)   // 196

// Output layout (floats, concatenated in reference return order)
#define O_ATT   0
#define O_CEW   (NE)
#define O_SEW   (2*NE)
#define O_MASK  (3*NE)
#define O_CEI   (4*NE)            // 2*NE entries: new_row then new_col
#define O_NMASK (6*NE)            // NNODES entries
#define O_CX    (6*NE + NNODES)   // NNODES*HID entries

// ---------------- edge attention MLP ----------------
// att[e] = relu(concat(emb[row],emb[col]) @ W1 + b1) @ W2 + b2
// Block: 256 threads, 128 edges. j-tiles of 128 (4), k-tiles of 32 (8).
// Thread tile: 8 edges x 8 j (te = t&15 -> edges te*8.., tj = t>>4 -> j tj*8..)
#define TE_  128
#define PAD_ 132

__global__ __launch_bounds__(256)
void att_kernel(const float* __restrict__ emb, const int* __restrict__ ei,
                const float* __restrict__ W1, const float* __restrict__ b1,
                const float* __restrict__ W2, const float* __restrict__ b2,
                float* __restrict__ out)
{
    __shared__ __align__(16) float Xs[32 * PAD_];
    __shared__ __align__(16) float Ws[32 * PAD_];
    __shared__ int sidx[TE_], cidx[TE_];

    const int t  = threadIdx.x;
    const int e0 = blockIdx.x * TE_;
    if (t < TE_) { sidx[t] = ei[e0 + t]; cidx[t] = ei[NE + e0 + t]; }
    __syncthreads();

    const int te = t & 15;
    const int tj = t >> 4;

    float attp[8];
#pragma unroll
    for (int a = 0; a < 8; ++a) attp[a] = 0.0f;

    for (int jt = 0; jt < 4; ++jt) {
        float acc[8][8];
#pragma unroll
        for (int a = 0; a < 8; ++a)
#pragma unroll
            for (int b = 0; b < 8; ++b) acc[a][b] = 0.0f;

        for (int kt = 0; kt < 8; ++kt) {
            __syncthreads();   // previous tile consumed
            // stage X: 32 k x 128 e, gathered. float4 along k.
#pragma unroll
            for (int i = 0; i < 4; ++i) {
                int flat = i * 256 + t;           // 0..1023
                int e  = flat >> 3;
                int k4 = flat & 7;
                int k  = kt * 32 + k4 * 4;
                const float* src;
                if (k < HID) src = emb + (long)sidx[e] * HID + k;
                else         src = emb + (long)cidx[e] * HID + (k - HID);
                float4 v = *(const float4*)src;
                int kl = k4 * 4;
                Xs[(kl + 0) * PAD_ + e] = v.x;
                Xs[(kl + 1) * PAD_ + e] = v.y;
                Xs[(kl + 2) * PAD_ + e] = v.z;
                Xs[(kl + 3) * PAD_ + e] = v.w;
            }
            // stage W1 tile: 32 k x 128 j
#pragma unroll
            for (int i = 0; i < 4; ++i) {
                int flat = i * 256 + t;           // 0..1023
                int kl = flat >> 5;
                int j4 = flat & 31;
                float4 v = *(const float4*)&W1[(kt * 32 + kl) * 512 + jt * 128 + j4 * 4];
                *(float4*)&Ws[kl * PAD_ + j4 * 4] = v;
            }
            __syncthreads();

#pragma unroll 4
            for (int kl = 0; kl < 32; ++kl) {
                float4 xa = *(const float4*)&Xs[kl * PAD_ + te * 8];
                float4 xb = *(const float4*)&Xs[kl * PAD_ + te * 8 + 4];
                float4 wa = *(const float4*)&Ws[kl * PAD_ + tj * 8];
                float4 wb = *(const float4*)&Ws[kl * PAD_ + tj * 8 + 4];
                float xv[8] = {xa.x, xa.y, xa.z, xa.w, xb.x, xb.y, xb.z, xb.w};
                float wv[8] = {wa.x, wa.y, wa.z, wa.w, wb.x, wb.y, wb.z, wb.w};
#pragma unroll
                for (int a = 0; a < 8; ++a)
#pragma unroll
                    for (int b = 0; b < 8; ++b)
                        acc[a][b] = fmaf(xv[a], wv[b], acc[a][b]);
            }
        }
        // epilogue for this j-tile: relu(+b1) * W2, accumulate per-edge partial
        int jb = jt * 128 + tj * 8;
        float4 b1a = *(const float4*)&b1[jb];
        float4 b1b = *(const float4*)&b1[jb + 4];
        float4 w2a = *(const float4*)&W2[jb];
        float4 w2b = *(const float4*)&W2[jb + 4];
        float bv[8] = {b1a.x, b1a.y, b1a.z, b1a.w, b1b.x, b1b.y, b1b.z, b1b.w};
        float wv[8] = {w2a.x, w2a.y, w2a.z, w2a.w, w2b.x, w2b.y, w2b.z, w2b.w};
#pragma unroll
        for (int a = 0; a < 8; ++a)
#pragma unroll
            for (int b = 0; b < 8; ++b) {
                float h = acc[a][b] + bv[b];
                h = fmaxf(h, 0.0f);
                attp[a] = fmaf(h, wv[b], attp[a]);
            }
    }

    // reduce att partials across the 16 tj-threads of each edge
    __syncthreads();
    float* red = Xs;   // reuse: need 16*136 = 2176 floats
#pragma unroll
    for (int a = 0; a < 8; ++a) red[tj * 136 + te * 8 + a] = attp[a];
    __syncthreads();
    if (t < TE_) {
        float s = 0.0f;
#pragma unroll
        for (int q = 0; q < 16; ++q) s += red[q * 136 + t];
        s += b2[0];
        out[O_ATT + e0 + t] = s;
    }
}

// ---------------- per-graph top-k ----------------
__device__ __forceinline__ unsigned enc_key(float f) {
    unsigned u = __float_as_uint(f);
    return (u & 0x80000000u) ? ~u : (u | 0x80000000u);
}
__device__ __forceinline__ float dec_key(unsigned k) {
    unsigned u = (k & 0x80000000u) ? (k ^ 0x80000000u) : ~k;
    return __uint_as_float(u);
}

__global__ __launch_bounds__(256)
void topk_kernel(const int* __restrict__ ei, float* __restrict__ out,
                 float* __restrict__ deg)
{
    __shared__ unsigned keys[EPG];
    __shared__ int eqoff[256];
    __shared__ int cnt;

    const int g  = blockIdx.x;
    const int t  = threadIdx.x;
    const int e0 = g * EPG;

    for (int idx = t; idx < EPG; idx += 256)
        keys[idx] = enc_key(out[O_ATT + e0 + idx]);
    __syncthreads();

    // binary search for K = max T with count(key >= T) >= KSEL
    unsigned lo = 0u, hi = 0xFFFFFFFFu;
    const int cbase = t * 16;            // blocked chunk, threads 0..249 active
    while (lo < hi) {
        unsigned mid = lo + ((hi - lo) >> 1) + 1u;
        if (t == 0) cnt = 0;
        __syncthreads();
        int c = 0;
        if (t < 250) {
#pragma unroll
            for (int q = 0; q < 16; ++q) c += (keys[cbase + q] >= mid) ? 1 : 0;
        }
        if (c) atomicAdd(&cnt, c);
        __syncthreads();
        int f = cnt;
        if (f >= KSEL) lo = mid; else hi = mid - 1u;
        __syncthreads();
    }
    const unsigned K = lo;

    // strictly-greater count
    if (t == 0) cnt = 0;
    __syncthreads();
    {
        int c = 0;
        if (t < 250) {
#pragma unroll
            for (int q = 0; q < 16; ++q) c += (keys[cbase + q] > K) ? 1 : 0;
        }
        if (c) atomicAdd(&cnt, c);
    }
    __syncthreads();
    const int r = KSEL - cnt;   // how many ==K ties to keep (by ascending index)

    // per-thread count of ==K, serial exclusive scan (tiny)
    int eqc = 0;
    if (t < 250) {
#pragma unroll
        for (int q = 0; q < 16; ++q) eqc += (keys[cbase + q] == K) ? 1 : 0;
    }
    eqoff[t] = eqc;
    __syncthreads();
    if (t == 0) {
        int s = 0;
        for (int i = 0; i < 256; ++i) { int v = eqoff[i]; eqoff[i] = s; s += v; }
    }
    __syncthreads();

    int run = eqoff[t];
    if (t < 250) {
        for (int q = 0; q < 16; ++q) {
            int e = cbase + q;
            unsigned kk = keys[e];
            bool eq = (kk == K);
            bool flag = (kk > K) || (eq && run < r);
            if (eq) run++;
            float a = dec_key(kk);
            int ge = e0 + e;
            out[O_CEW + ge]  = flag ? a : 0.0f;
            out[O_SEW + ge]  = flag ? 0.0f : a;
            out[O_MASK + ge] = flag ? 1.0f : 0.0f;
            if (flag) {
                int row = ei[ge];
                int col = ei[NE + ge];
                atomicAdd(&deg[row], 1.0f);
                atomicAdd(&deg[col], 1.0f);
            }
        }
    }
}

// ---------------- node relabel: global prefix scan over node_mask ----------------
__global__ __launch_bounds__(256)
void scanA(const float* __restrict__ deg, int* __restrict__ partials)
{
    __shared__ int s[256];
    int t = threadIdx.x;
    int n = blockIdx.x * 256 + t;
    int m = (n < NNODES && deg[n] > 0.5f) ? 1 : 0;
    s[t] = m;
    __syncthreads();
    for (int off = 128; off > 0; off >>= 1) {
        if (t < off) s[t] += s[t + off];
        __syncthreads();
    }
    if (t == 0) partials[blockIdx.x] = s[0];
}

__global__ __launch_bounds__(256)
void scanB(int* __restrict__ partials)
{
    __shared__ int s[256];
    int t = threadIdx.x;
    int v = (t < NB_SCAN) ? partials[t] : 0;
    s[t] = v;
    __syncthreads();
    for (int off = 1; off < 256; off <<= 1) {
        int x = (t >= off) ? s[t - off] : 0;
        __syncthreads();
        s[t] += x;
        __syncthreads();
    }
    if (t < NB_SCAN) partials[t] = s[t] - v;   // exclusive prefix
}

__global__ __launch_bounds__(256)
void scanC(float* __restrict__ deg_nm, const int* __restrict__ partials,
           int* __restrict__ newid)
{
    __shared__ int s[256];
    int t = threadIdx.x;
    int b = blockIdx.x;
    int n = b * 256 + t;
    int m = (n < NNODES && deg_nm[n] > 0.5f) ? 1 : 0;
    s[t] = m;
    __syncthreads();
    for (int off = 1; off < 256; off <<= 1) {
        int x = (t >= off) ? s[t - off] : 0;
        __syncthreads();
        s[t] += x;
        __syncthreads();
    }
    if (n < NNODES) {
        newid[n]  = partials[b] + s[t] - 1;   // cumsum(mask)-1
        deg_nm[n] = m ? 1.0f : 0.0f;          // finalize node_mask output
    }
}

__global__ __launch_bounds__(256)
void edges_final(const int* __restrict__ ei, const int* __restrict__ newid,
                 float* __restrict__ out)
{
    int e = blockIdx.x * 256 + threadIdx.x;
    if (e >= NE) return;
    bool flag = out[O_MASK + e] > 0.5f;
    int row = ei[e];
    int col = ei[NE + e];
    out[O_CEI + e]      = flag ? (float)newid[row] : -1.0f;
    out[O_CEI + NE + e] = flag ? (float)newid[col] : -1.0f;
}

__global__ __launch_bounds__(256)
void causal_x_kernel(const float* __restrict__ emb, const float* __restrict__ nm,
                     float* __restrict__ out)
{
    int i4 = blockIdx.x * 256 + threadIdx.x;       // float4 index
    if (i4 >= NNODES * HID / 4) return;
    int n = i4 >> 5;                               // 32 float4 per node
    float4 v = ((const float4*)emb)[i4];
    if (!(nm[n] > 0.5f)) v = make_float4(0.0f, 0.0f, 0.0f, 0.0f);
    ((float4*)(out + O_CX))[i4] = v;
}

extern "C" void kernel_launch(void* const* d_in, const int* in_sizes, int n_in,
                              void* d_out, int out_size, void* d_ws, size_t ws_size,
                              hipStream_t stream)
{
    const float* emb = (const float*)d_in[0];
    const int*   ei  = (const int*)d_in[1];
    // d_in[2] = node_batch (implied by edge layout; unused)
    const float* W1  = (const float*)d_in[3];
    const float* b1  = (const float*)d_in[4];
    const float* W2  = (const float*)d_in[5];
    const float* b2  = (const float*)d_in[6];
    float* out = (float*)d_out;

    int* newid    = (int*)d_ws;                    // NNODES ints
    int* partials = newid + NNODES;                // NB_SCAN ints
    float* deg    = out + O_NMASK;                 // reuse node_mask region as deg accumulator

    hipMemsetAsync(deg, 0, NNODES * sizeof(float), stream);

    att_kernel<<<NE / TE_, 256, 0, stream>>>(emb, ei, W1, b1, W2, b2, out);
    topk_kernel<<<NG, 256, 0, stream>>>(ei, out, deg);
    scanA<<<NB_SCAN, 256, 0, stream>>>(deg, partials);
    scanB<<<1, 256, 0, stream>>>(partials);
    scanC<<<NB_SCAN, 256, 0, stream>>>(deg, partials, newid);
    edges_final<<<(NE + 255) / 256, 256, 0, stream>>>(ei, newid, out);
    causal_x_kernel<<<(NNODES * HID / 4 + 255) / 256, 256, 0, stream>>>(emb, deg, out);
}

// Round 4
// 792.380 us; speedup vs baseline: 1.7325x; 1.7325x over previous
//
#include <hip/hip_runtime.h>
#include <hip/hip_bf16.h>

// Problem constants (fixed by setup_inputs)
#define NG      100
#define NPG     500
#define EPG     4000
#define HID     128
#define NNODES  (NG*NPG)     // 50000
#define NE      (NG*EPG)     // 400000
#define KSEL    2000         // ceil(0.5*4000)
#define NB_SCAN ((NNODES + 255) / 256)   // 196

#define MAXB    1024         // boundary-list capacity per graph (expect ~140)
#define NRC     8            // repair chunks per graph (MAXB/128)
#define DELTA   0.03125f     // screening margin (~30 sigma of bf16 att error)

// Output layout (floats, concatenated in reference return order)
#define O_ATT   0
#define O_CEW   (NE)
#define O_SEW   (2*NE)
#define O_MASK  (3*NE)
#define O_CEI   (4*NE)            // 2*NE entries: new_row then new_col
#define O_NMASK (6*NE)            // NNODES entries
#define O_CX    (6*NE + NNODES)   // NNODES*HID entries

typedef __attribute__((ext_vector_type(8))) short  short8;
typedef __attribute__((ext_vector_type(8))) __bf16 bf16x8;
typedef __attribute__((ext_vector_type(4))) float  f32x4;

#define MFMA16(a,b,c) __builtin_amdgcn_mfma_f32_16x16x32_bf16( \
    __builtin_bit_cast(bf16x8,(a)), __builtin_bit_cast(bf16x8,(b)), (c), 0, 0, 0)

#define GLOAD_LDS16(g, l) __builtin_amdgcn_global_load_lds( \
    (const __attribute__((address_space(1))) unsigned int*)(g), \
    (__attribute__((address_space(3)))       unsigned int*)(l), 16, 0, 0)

__device__ __forceinline__ unsigned short tobf(float x) {
    __hip_bfloat16 hb = __float2bfloat16(x);
    return *(unsigned short*)&hb;
}

// ---------------- preprocessing: emb -> bf16 (RNE) ----------------
__global__ __launch_bounds__(256)
void tobf_kernel(const float* __restrict__ emb, unsigned short* __restrict__ eb)
{
    int i = blockIdx.x * 256 + threadIdx.x;          // float4 index, 1.6M total
    float4 v = ((const float4*)emb)[i];
    ushort4 h;
    h.x = tobf(v.x); h.y = tobf(v.y); h.z = tobf(v.z); h.w = tobf(v.w);
    ((ushort4*)eb)[i] = h;
}

// ---------------- preprocessing: pack W1 bf16 into B-fragment order -------
// 16x16x32 operand layout: fragment col = lane&15, k = (lane>>4)*8 + i.
// Packed idx = g*512 + lane*8 + i with g = (kc*8 + jo)*4 + jsub;
//   j = jo*64 + jsub*16 + (lane&15);  k = kc*32 + (lane>>4)*8 + i
__global__ __launch_bounds__(256)
void pack_w1_kernel(const float* __restrict__ W1, unsigned short* __restrict__ ph)
{
    int idx  = blockIdx.x * 256 + threadIdx.x;       // 131072 total
    int i    = idx & 7;
    int lane = (idx >> 3) & 63;
    int g    = idx >> 9;
    int jsub = g & 3;
    int rem  = g >> 2;
    int jo   = rem & 7;
    int kc   = rem >> 3;                             // 0..7
    int j = jo * 64 + jsub * 16 + (lane & 15);
    int k = kc * 32 + (lane >> 4) * 8 + i;
    ph[idx] = tobf(W1[k * 512 + j]);
}

// ---------------- screening GEMM: plain bf16 MFMA ----------------
// Block: 256 threads = 4 waves; 64 edges/wave (4 M-tiles of 16) -> 256/block.
// j: 8 outer tiles of 64 (4 mfma j-tiles of 16). k: 2 halves (src/dst) x 4
// chunks of 32.
__global__ __launch_bounds__(256)
void att4_kernel(const unsigned short* __restrict__ embb,
                 const unsigned short* __restrict__ w1p,
                 const int* __restrict__ ei,
                 const float* __restrict__ b1,
                 const float* __restrict__ W2,
                 const float* __restrict__ b2,
                 float* __restrict__ out)
{
    // 16 chunks x 512 bf16 (1 KB each): c = kc4*4 + jsub
    __shared__ __align__(16) unsigned short ldsB[8192];   // 16 KB

    const int t    = threadIdx.x;
    const int w    = t >> 6;        // wave 0..3
    const int lane = t & 63;
    const int r16  = lane & 15;
    const int quad = lane >> 4;

    const int e_base = blockIdx.x * 256 + w * 64;
    int sb[4], db[4];
#pragma unroll
    for (int mt = 0; mt < 4; ++mt) {
        int e = min(e_base + mt * 16 + r16, NE - 1);
        sb[mt] = ei[e] << 8;                  // byte base, 256 B per node row
        db[mt] = ei[NE + e] << 8;
    }

    const char* eb = (const char*)embb;

    float attP[4][4];
#pragma unroll
    for (int mt = 0; mt < 4; ++mt)
#pragma unroll
        for (int rg = 0; rg < 4; ++rg) attP[mt][rg] = 0.0f;

    for (int jo = 0; jo < 8; ++jo) {
        f32x4 acc[4][4];   // [mt][jsub]
#pragma unroll
        for (int mt = 0; mt < 4; ++mt)
#pragma unroll
            for (int js = 0; js < 4; ++js) acc[mt][js] = f32x4{};

        for (int kH = 0; kH < 2; ++kH) {
            __syncthreads();   // prior-iteration LDS reads complete
            // stage 16 chunks; wave w stages chunks w*4 .. w*4+3
#pragma unroll
            for (int cc = 0; cc < 4; ++cc) {
                int c    = w * 4 + cc;
                int kc4  = c >> 2;
                int jsub = c & 3;
                int kc   = kH * 4 + kc4;
                int g    = (kc * 8 + jo) * 4 + jsub;
                GLOAD_LDS16(w1p + g * 512 + lane * 8, ldsB + c * 512);
            }
            __syncthreads();

#pragma unroll
            for (int kc4 = 0; kc4 < 4; ++kc4) {
                const int off = kc4 * 64 + quad * 16;   // bytes within half-row
                short8 A[4];
#pragma unroll
                for (int mt = 0; mt < 4; ++mt)
                    A[mt] = *(const short8*)(eb + (kH ? db[mt] : sb[mt]) + off);
#pragma unroll
                for (int jsub = 0; jsub < 4; ++jsub) {
                    short8 B = *(const short8*)(ldsB + (kc4 * 4 + jsub) * 512 + lane * 8);
#pragma unroll
                    for (int mt = 0; mt < 4; ++mt)
                        acc[mt][jsub] = MFMA16(A[mt], B, acc[mt][jsub]);
                }
            }
        }

        // epilogue: h = relu(y + b1[j]); attP += h * W2[j]   (j col = r16)
#pragma unroll
        for (int jsub = 0; jsub < 4; ++jsub) {
            const int j = jo * 64 + jsub * 16 + r16;
            const float b1v = b1[j], w2v = W2[j];
#pragma unroll
            for (int mt = 0; mt < 4; ++mt)
#pragma unroll
                for (int rg = 0; rg < 4; ++rg)
                    attP[mt][rg] += fmaxf(acc[mt][jsub][rg] + b1v, 0.0f) * w2v;
        }
    }

    // sum over the 16 j-columns: butterfly over low 4 lane bits
#pragma unroll
    for (int mt = 0; mt < 4; ++mt)
#pragma unroll
        for (int rg = 0; rg < 4; ++rg) {
            float v = attP[mt][rg];
#pragma unroll
            for (int msk = 1; msk <= 8; msk <<= 1) v += __shfl_xor(v, msk, 64);
            attP[mt][rg] = v;
        }

    const float bias2 = b2[0];
    if (r16 < 4) {
#pragma unroll
        for (int mt = 0; mt < 4; ++mt) {
            const int row = quad * 4 + r16;    // C/D row = (lane>>4)*4 + reg
            const int e   = e_base + mt * 16 + row;
            if (e < NE) out[O_ATT + e] = attP[mt][r16] + bias2;
        }
    }
}

// ---------------- per-graph top-k screening ----------------
__device__ __forceinline__ unsigned enc_key(float f) {
    unsigned u = __float_as_uint(f);
    return (u & 0x80000000u) ? ~u : (u | 0x80000000u);
}
__device__ __forceinline__ float dec_key(unsigned k) {
    unsigned u = (k & 0x80000000u) ? (k ^ 0x80000000u) : ~k;
    return __uint_as_float(u);
}

__global__ __launch_bounds__(256)
void topk4_kernel(const int* __restrict__ ei, float* __restrict__ out,
                  float* __restrict__ deg, int* __restrict__ bcnt,
                  int* __restrict__ need, int* __restrict__ blist)
{
    __shared__ unsigned keys[EPG];
    __shared__ int cnt;

    const int g  = blockIdx.x;
    const int t  = threadIdx.x;
    const int e0 = g * EPG;

    for (int idx = t; idx < EPG; idx += 256)
        keys[idx] = enc_key(out[O_ATT + e0 + idx]);
    __syncthreads();

    // binary search for K = max T with count(key >= T) >= KSEL
    unsigned lo = 0u, hi = 0xFFFFFFFFu;
    const int cbase = t * 16;            // blocked chunk, threads 0..249 active
    while (lo < hi) {
        unsigned mid = lo + ((hi - lo) >> 1) + 1u;
        if (t == 0) cnt = 0;
        __syncthreads();
        int c = 0;
        if (t < 250) {
#pragma unroll
            for (int q = 0; q < 16; ++q) c += (keys[cbase + q] >= mid) ? 1 : 0;
        }
        if (c) atomicAdd(&cnt, c);
        __syncthreads();
        int f = cnt;
        if (f >= KSEL) lo = mid; else hi = mid - 1u;
        __syncthreads();
    }
    const unsigned K = lo;
    const float v = dec_key(K);
    const unsigned khi = enc_key(v + DELTA);
    const unsigned klo = enc_key(v - DELTA);

    // in_cnt = #{key > khi}
    if (t == 0) cnt = 0;
    __syncthreads();
    {
        int c = 0;
        if (t < 250) {
#pragma unroll
            for (int q = 0; q < 16; ++q) c += (keys[cbase + q] > khi) ? 1 : 0;
        }
        if (c) atomicAdd(&cnt, c);
    }
    __syncthreads();
    if (t == 0) need[g] = KSEL - cnt;

    // classify and emit; boundary edges deferred to blist
    for (int idx = t; idx < EPG; idx += 256) {
        unsigned kk = keys[idx];
        int ge = e0 + idx;
        float a = dec_key(kk);
        if (kk > khi) {
            out[O_CEW + ge]  = a;
            out[O_SEW + ge]  = 0.0f;
            out[O_MASK + ge] = 1.0f;
            atomicAdd(&deg[ei[ge]], 1.0f);
            atomicAdd(&deg[ei[NE + ge]], 1.0f);
        } else if (kk < klo) {
            out[O_CEW + ge]  = 0.0f;
            out[O_SEW + ge]  = a;
            out[O_MASK + ge] = 0.0f;
        } else {
            int p = atomicAdd(&bcnt[g], 1);
            if (p < MAXB) blist[g * MAXB + p] = ge;
        }
    }
}

// ---------------- exact fp32 recompute of boundary edges ----------------
// Round-1's (passed) fp32 MLP kernel, gather-list variant.
#define TE_  128
#define PAD_ 132

__global__ __launch_bounds__(256)
void repair_kernel(const float* __restrict__ emb, const int* __restrict__ ei,
                   const float* __restrict__ W1, const float* __restrict__ b1,
                   const float* __restrict__ W2, const float* __restrict__ b2,
                   const int* __restrict__ bcnt, const int* __restrict__ blist,
                   float* __restrict__ attx)
{
    const int blk = blockIdx.x;
    const int g   = blk >> 3;          // NRC = 8
    const int ch  = blk & 7;
    const int bc  = min(bcnt[g], MAXB);
    if (ch * 128 >= bc) return;

    __shared__ __align__(16) float Xs[32 * PAD_];
    __shared__ __align__(16) float Ws[32 * PAD_];
    __shared__ int sidx[TE_], cidx[TE_];

    const int t = threadIdx.x;
    if (t < TE_) {
        int lid = ch * 128 + t;
        int lc  = min(lid, bc - 1);
        int e   = blist[g * MAXB + lc];
        sidx[t] = ei[e];
        cidx[t] = ei[NE + e];
    }
    __syncthreads();

    const int te = t & 15;
    const int tj = t >> 4;

    float attp[8];
#pragma unroll
    for (int a = 0; a < 8; ++a) attp[a] = 0.0f;

    for (int jt = 0; jt < 4; ++jt) {
        float acc[8][8];
#pragma unroll
        for (int a = 0; a < 8; ++a)
#pragma unroll
            for (int b = 0; b < 8; ++b) acc[a][b] = 0.0f;

        for (int kt = 0; kt < 8; ++kt) {
            __syncthreads();
#pragma unroll
            for (int i = 0; i < 4; ++i) {
                int flat = i * 256 + t;
                int e  = flat >> 3;
                int k4 = flat & 7;
                int k  = kt * 32 + k4 * 4;
                const float* src;
                if (k < HID) src = emb + (long)sidx[e] * HID + k;
                else         src = emb + (long)cidx[e] * HID + (k - HID);
                float4 v = *(const float4*)src;
                int kl = k4 * 4;
                Xs[(kl + 0) * PAD_ + e] = v.x;
                Xs[(kl + 1) * PAD_ + e] = v.y;
                Xs[(kl + 2) * PAD_ + e] = v.z;
                Xs[(kl + 3) * PAD_ + e] = v.w;
            }
#pragma unroll
            for (int i = 0; i < 4; ++i) {
                int flat = i * 256 + t;
                int kl = flat >> 5;
                int j4 = flat & 31;
                float4 v = *(const float4*)&W1[(kt * 32 + kl) * 512 + jt * 128 + j4 * 4];
                *(float4*)&Ws[kl * PAD_ + j4 * 4] = v;
            }
            __syncthreads();

#pragma unroll 4
            for (int kl = 0; kl < 32; ++kl) {
                float4 xa = *(const float4*)&Xs[kl * PAD_ + te * 8];
                float4 xb = *(const float4*)&Xs[kl * PAD_ + te * 8 + 4];
                float4 wa = *(const float4*)&Ws[kl * PAD_ + tj * 8];
                float4 wb = *(const float4*)&Ws[kl * PAD_ + tj * 8 + 4];
                float xv[8] = {xa.x, xa.y, xa.z, xa.w, xb.x, xb.y, xb.z, xb.w};
                float wv[8] = {wa.x, wa.y, wa.z, wa.w, wb.x, wb.y, wb.z, wb.w};
#pragma unroll
                for (int a = 0; a < 8; ++a)
#pragma unroll
                    for (int b = 0; b < 8; ++b)
                        acc[a][b] = fmaf(xv[a], wv[b], acc[a][b]);
            }
        }
        int jb = jt * 128 + tj * 8;
        float4 b1a = *(const float4*)&b1[jb];
        float4 b1b = *(const float4*)&b1[jb + 4];
        float4 w2a = *(const float4*)&W2[jb];
        float4 w2b = *(const float4*)&W2[jb + 4];
        float bv[8] = {b1a.x, b1a.y, b1a.z, b1a.w, b1b.x, b1b.y, b1b.z, b1b.w};
        float wv[8] = {w2a.x, w2a.y, w2a.z, w2a.w, w2b.x, w2b.y, w2b.z, w2b.w};
#pragma unroll
        for (int a = 0; a < 8; ++a)
#pragma unroll
            for (int b = 0; b < 8; ++b) {
                float h = acc[a][b] + bv[b];
                h = fmaxf(h, 0.0f);
                attp[a] = fmaf(h, wv[b], attp[a]);
            }
    }

    __syncthreads();
    float* red = Xs;
#pragma unroll
    for (int a = 0; a < 8; ++a) red[tj * 136 + te * 8 + a] = attp[a];
    __syncthreads();
    if (t < TE_ && ch * 128 + t < bc) {
        float s = 0.0f;
#pragma unroll
        for (int q = 0; q < 16; ++q) s += red[q * 136 + t];
        attx[g * MAXB + ch * 128 + t] = s + b2[0];
    }
}

// ---------------- exact selection among boundary edges ----------------
__global__ __launch_bounds__(256)
void select_kernel(const int* __restrict__ ei, const int* __restrict__ bcnt,
                   const int* __restrict__ need, const int* __restrict__ blist,
                   const float* __restrict__ attx, float* __restrict__ out,
                   float* __restrict__ deg)
{
    __shared__ float sa[MAXB];
    __shared__ int   si[MAXB];
    const int g = blockIdx.x;
    const int t = threadIdx.x;
    const int b = min(bcnt[g], MAXB);
    const int n = need[g];

    for (int i = t; i < b; i += 256) {
        sa[i] = attx[g * MAXB + i];
        si[i] = blist[g * MAXB + i];
    }
    __syncthreads();

    for (int i = t; i < b; i += 256) {
        float ai = sa[i];
        int   ii = si[i];
        int rank = 0;
        for (int j = 0; j < b; ++j)
            rank += (sa[j] > ai || (sa[j] == ai && si[j] < ii)) ? 1 : 0;
        bool flag = rank < n;
        out[O_CEW + ii]  = flag ? ai : 0.0f;
        out[O_SEW + ii]  = flag ? 0.0f : ai;
        out[O_MASK + ii] = flag ? 1.0f : 0.0f;
        if (flag) {
            atomicAdd(&deg[ei[ii]], 1.0f);
            atomicAdd(&deg[ei[NE + ii]], 1.0f);
        }
    }
}

// ---------------- node relabel: global prefix scan over node_mask ----------------
__global__ __launch_bounds__(256)
void scanA(const float* __restrict__ deg, int* __restrict__ partials)
{
    __shared__ int s[256];
    int t = threadIdx.x;
    int n = blockIdx.x * 256 + t;
    int m = (n < NNODES && deg[n] > 0.5f) ? 1 : 0;
    s[t] = m;
    __syncthreads();
    for (int off = 128; off > 0; off >>= 1) {
        if (t < off) s[t] += s[t + off];
        __syncthreads();
    }
    if (t == 0) partials[blockIdx.x] = s[0];
}

__global__ __launch_bounds__(256)
void scanB(int* __restrict__ partials)
{
    __shared__ int s[256];
    int t = threadIdx.x;
    int v = (t < NB_SCAN) ? partials[t] : 0;
    s[t] = v;
    __syncthreads();
    for (int off = 1; off < 256; off <<= 1) {
        int x = (t >= off) ? s[t - off] : 0;
        __syncthreads();
        s[t] += x;
        __syncthreads();
    }
    if (t < NB_SCAN) partials[t] = s[t] - v;   // exclusive prefix
}

__global__ __launch_bounds__(256)
void scanC(float* __restrict__ deg_nm, const int* __restrict__ partials,
           int* __restrict__ newid)
{
    __shared__ int s[256];
    int t = threadIdx.x;
    int b = blockIdx.x;
    int n = b * 256 + t;
    int m = (n < NNODES && deg_nm[n] > 0.5f) ? 1 : 0;
    s[t] = m;
    __syncthreads();
    for (int off = 1; off < 256; off <<= 1) {
        int x = (t >= off) ? s[t - off] : 0;
        __syncthreads();
        s[t] += x;
        __syncthreads();
    }
    if (n < NNODES) {
        newid[n]  = partials[b] + s[t] - 1;   // cumsum(mask)-1
        deg_nm[n] = m ? 1.0f : 0.0f;          // finalize node_mask output
    }
}

__global__ __launch_bounds__(256)
void edges_final(const int* __restrict__ ei, const int* __restrict__ newid,
                 float* __restrict__ out)
{
    int e = blockIdx.x * 256 + threadIdx.x;
    if (e >= NE) return;
    bool flag = out[O_MASK + e] > 0.5f;
    int row = ei[e];
    int col = ei[NE + e];
    out[O_CEI + e]      = flag ? (float)newid[row] : -1.0f;
    out[O_CEI + NE + e] = flag ? (float)newid[col] : -1.0f;
}

__global__ __launch_bounds__(256)
void causal_x_kernel(const float* __restrict__ emb, const float* __restrict__ nm,
                     float* __restrict__ out)
{
    int i4 = blockIdx.x * 256 + threadIdx.x;       // float4 index
    if (i4 >= NNODES * HID / 4) return;
    int n = i4 >> 5;                               // 32 float4 per node
    float4 v = ((const float4*)emb)[i4];
    if (!(nm[n] > 0.5f)) v = make_float4(0.0f, 0.0f, 0.0f, 0.0f);
    ((float4*)(out + O_CX))[i4] = v;
}

extern "C" void kernel_launch(void* const* d_in, const int* in_sizes, int n_in,
                              void* d_out, int out_size, void* d_ws, size_t ws_size,
                              hipStream_t stream)
{
    const float* emb = (const float*)d_in[0];
    const int*   ei  = (const int*)d_in[1];
    // d_in[2] = node_batch (implied by edge layout; unused)
    const float* W1  = (const float*)d_in[3];
    const float* b1  = (const float*)d_in[4];
    const float* W2  = (const float*)d_in[5];
    const float* b2  = (const float*)d_in[6];
    float* out = (float*)d_out;

    char* wsb = (char*)d_ws;
    int*   newid    = (int*)wsb;                          // 200000 B
    int*   partials = (int*)(wsb + 200704);
    int*   bcnt     = (int*)(wsb + 201728);               // NG ints
    int*   need     = (int*)(wsb + 202752);               // NG ints
    int*   blist    = (int*)(wsb + 203776);               // NG*MAXB ints (400 KB)
    float* attx     = (float*)(wsb + 203776 + NG*MAXB*4); // NG*MAXB floats
    unsigned short* embb = (unsigned short*)(wsb + 203776 + 2*NG*MAXB*4); // 12.8 MB
    unsigned short* w1p  = embb + NNODES * HID;           // 131072 bf16
    float* deg = out + O_NMASK;                           // node_mask region as deg accum

    hipMemsetAsync(deg, 0, NNODES * sizeof(float), stream);
    hipMemsetAsync(bcnt, 0, NG * sizeof(int), stream);

    tobf_kernel<<<NNODES * HID / 4 / 256, 256, 0, stream>>>(emb, embb);
    pack_w1_kernel<<<512, 256, 0, stream>>>(W1, w1p);
    att4_kernel<<<(NE + 255) / 256, 256, 0, stream>>>(embb, w1p, ei, b1, W2, b2, out);
    topk4_kernel<<<NG, 256, 0, stream>>>(ei, out, deg, bcnt, need, blist);
    repair_kernel<<<NG * NRC, 256, 0, stream>>>(emb, ei, W1, b1, W2, b2,
                                                bcnt, blist, attx);
    select_kernel<<<NG, 256, 0, stream>>>(ei, bcnt, need, blist, attx, out, deg);
    scanA<<<NB_SCAN, 256, 0, stream>>>(deg, partials);
    scanB<<<1, 256, 0, stream>>>(partials);
    scanC<<<NB_SCAN, 256, 0, stream>>>(deg, partials, newid);
    edges_final<<<(NE + 255) / 256, 256, 0, stream>>>(ei, newid, out);
    causal_x_kernel<<<(NNODES * HID / 4 + 255) / 256, 256, 0, stream>>>(emb, deg, out);
}

// Round 5
// 561.291 us; speedup vs baseline: 2.4458x; 1.4117x over previous
//
#include <hip/hip_runtime.h>
#include <hip/hip_bf16.h>

// Problem constants (fixed by setup_inputs)
#define NG      100
#define NPG     500
#define EPG     4000
#define HID     128
#define NNODES  (NG*NPG)     // 50000
#define NE      (NG*EPG)     // 400000
#define KSEL    2000         // ceil(0.5*4000)
#define NB_SCAN ((NNODES + 255) / 256)   // 196

#define MAXB    1024         // boundary-list capacity per graph (expect ~140)
#define NRC     8            // repair chunks per graph (MAXB/128)
#define RJT     8            // repair j-tiles (512/64)
#define DELTA   0.03125f     // screening margin (~22 sigma of bf16 att error)

// Output layout (floats, concatenated in reference return order)
#define O_ATT   0
#define O_CEW   (NE)
#define O_SEW   (2*NE)
#define O_MASK  (3*NE)
#define O_CEI   (4*NE)            // 2*NE entries: new_row then new_col
#define O_NMASK (6*NE)            // NNODES entries
#define O_CX    (6*NE + NNODES)   // NNODES*HID entries

typedef __attribute__((ext_vector_type(8))) short  short8;
typedef __attribute__((ext_vector_type(8))) __bf16 bf16x8;
typedef __attribute__((ext_vector_type(4))) float  f32x4;

#define MFMA16(a,b,c) __builtin_amdgcn_mfma_f32_16x16x32_bf16( \
    __builtin_bit_cast(bf16x8,(a)), __builtin_bit_cast(bf16x8,(b)), (c), 0, 0, 0)

#define GLOAD_LDS16(g, l) __builtin_amdgcn_global_load_lds( \
    (const __attribute__((address_space(1))) unsigned int*)(g), \
    (__attribute__((address_space(3)))       unsigned int*)(l), 16, 0, 0)

__device__ __forceinline__ unsigned short tobf(float x) {
    __hip_bfloat16 hb = __float2bfloat16(x);
    return *(unsigned short*)&hb;
}

// ---------------- preprocessing: emb -> bf16 (RNE) ----------------
__global__ __launch_bounds__(256)
void tobf_kernel(const float* __restrict__ emb, unsigned short* __restrict__ eb)
{
    int i = blockIdx.x * 256 + threadIdx.x;          // float4 index, 1.6M total
    float4 v = ((const float4*)emb)[i];
    ushort4 h;
    h.x = tobf(v.x); h.y = tobf(v.y); h.z = tobf(v.z); h.w = tobf(v.w);
    ((ushort4*)eb)[i] = h;
}

// ---------------- preprocessing: pack W1 bf16 into B-fragment order -------
// 16x16x32 operand layout: fragment col = lane&15, k = (lane>>4)*8 + i.
// Packed idx = g*512 + lane*8 + i with g = (kc*8 + jo)*4 + jsub;
//   j = jo*64 + jsub*16 + (lane&15);  k = kc*32 + (lane>>4)*8 + i
__global__ __launch_bounds__(256)
void pack_w1_kernel(const float* __restrict__ W1, unsigned short* __restrict__ ph)
{
    int idx  = blockIdx.x * 256 + threadIdx.x;       // 131072 total
    int i    = idx & 7;
    int lane = (idx >> 3) & 63;
    int g    = idx >> 9;
    int jsub = g & 3;
    int rem  = g >> 2;
    int jo   = rem & 7;
    int kc   = rem >> 3;                             // 0..7
    int j = jo * 64 + jsub * 16 + (lane & 15);
    int k = kc * 32 + (lane >> 4) * 8 + i;
    ph[idx] = tobf(W1[k * 512 + j]);
}

// ---------------- screening GEMM: plain bf16 MFMA ----------------
// Block: 256 threads = 4 waves; 64 edges/wave (4 M-tiles of 16) -> 256/block.
// j: 8 outer tiles of 64 (4 mfma j-tiles of 16). k: 2 halves (src/dst) x 4
// chunks of 32.
__global__ __launch_bounds__(256)
void att4_kernel(const unsigned short* __restrict__ embb,
                 const unsigned short* __restrict__ w1p,
                 const int* __restrict__ ei,
                 const float* __restrict__ b1,
                 const float* __restrict__ W2,
                 const float* __restrict__ b2,
                 float* __restrict__ out)
{
    // 16 chunks x 512 bf16 (1 KB each): c = kc4*4 + jsub
    __shared__ __align__(16) unsigned short ldsB[8192];   // 16 KB

    const int t    = threadIdx.x;
    const int w    = t >> 6;        // wave 0..3
    const int lane = t & 63;
    const int r16  = lane & 15;
    const int quad = lane >> 4;

    const int e_base = blockIdx.x * 256 + w * 64;
    int sb[4], db[4];
#pragma unroll
    for (int mt = 0; mt < 4; ++mt) {
        int e = min(e_base + mt * 16 + r16, NE - 1);
        sb[mt] = ei[e] << 8;                  // byte base, 256 B per node row
        db[mt] = ei[NE + e] << 8;
    }

    const char* eb = (const char*)embb;

    float attP[4][4];
#pragma unroll
    for (int mt = 0; mt < 4; ++mt)
#pragma unroll
        for (int rg = 0; rg < 4; ++rg) attP[mt][rg] = 0.0f;

    for (int jo = 0; jo < 8; ++jo) {
        f32x4 acc[4][4];   // [mt][jsub]
#pragma unroll
        for (int mt = 0; mt < 4; ++mt)
#pragma unroll
            for (int js = 0; js < 4; ++js) acc[mt][js] = f32x4{};

        for (int kH = 0; kH < 2; ++kH) {
            __syncthreads();   // prior-iteration LDS reads complete
            // stage 16 chunks; wave w stages chunks w*4 .. w*4+3
#pragma unroll
            for (int cc = 0; cc < 4; ++cc) {
                int c    = w * 4 + cc;
                int kc4  = c >> 2;
                int jsub = c & 3;
                int kc   = kH * 4 + kc4;
                int g    = (kc * 8 + jo) * 4 + jsub;
                GLOAD_LDS16(w1p + g * 512 + lane * 8, ldsB + c * 512);
            }
            __syncthreads();

#pragma unroll
            for (int kc4 = 0; kc4 < 4; ++kc4) {
                const int off = kc4 * 64 + quad * 16;   // bytes within half-row
                short8 A[4];
#pragma unroll
                for (int mt = 0; mt < 4; ++mt)
                    A[mt] = *(const short8*)(eb + (kH ? db[mt] : sb[mt]) + off);
#pragma unroll
                for (int jsub = 0; jsub < 4; ++jsub) {
                    short8 B = *(const short8*)(ldsB + (kc4 * 4 + jsub) * 512 + lane * 8);
#pragma unroll
                    for (int mt = 0; mt < 4; ++mt)
                        acc[mt][jsub] = MFMA16(A[mt], B, acc[mt][jsub]);
                }
            }
        }

        // epilogue: h = relu(y + b1[j]); attP += h * W2[j]   (j col = r16)
#pragma unroll
        for (int jsub = 0; jsub < 4; ++jsub) {
            const int j = jo * 64 + jsub * 16 + r16;
            const float b1v = b1[j], w2v = W2[j];
#pragma unroll
            for (int mt = 0; mt < 4; ++mt)
#pragma unroll
                for (int rg = 0; rg < 4; ++rg)
                    attP[mt][rg] += fmaxf(acc[mt][jsub][rg] + b1v, 0.0f) * w2v;
        }
    }

    // sum over the 16 j-columns: butterfly over low 4 lane bits
#pragma unroll
    for (int mt = 0; mt < 4; ++mt)
#pragma unroll
        for (int rg = 0; rg < 4; ++rg) {
            float v = attP[mt][rg];
#pragma unroll
            for (int msk = 1; msk <= 8; msk <<= 1) v += __shfl_xor(v, msk, 64);
            attP[mt][rg] = v;
        }

    const float bias2 = b2[0];
    if (r16 < 4) {
#pragma unroll
        for (int mt = 0; mt < 4; ++mt) {
            const int row = quad * 4 + r16;    // C/D row = (lane>>4)*4 + reg
            const int e   = e_base + mt * 16 + row;
            if (e < NE) out[O_ATT + e] = attP[mt][r16] + bias2;
        }
    }
}

// ---------------- per-graph top-k screening ----------------
__device__ __forceinline__ unsigned enc_key(float f) {
    unsigned u = __float_as_uint(f);
    return (u & 0x80000000u) ? ~u : (u | 0x80000000u);
}
__device__ __forceinline__ float dec_key(unsigned k) {
    unsigned u = (k & 0x80000000u) ? (k ^ 0x80000000u) : ~k;
    return __uint_as_float(u);
}

__global__ __launch_bounds__(256)
void topk4_kernel(const int* __restrict__ ei, float* __restrict__ out,
                  float* __restrict__ deg, int* __restrict__ bcnt,
                  int* __restrict__ need, int* __restrict__ blist)
{
    __shared__ unsigned keys[EPG];
    __shared__ int cnt;

    const int g  = blockIdx.x;
    const int t  = threadIdx.x;
    const int e0 = g * EPG;

    for (int idx = t; idx < EPG; idx += 256)
        keys[idx] = enc_key(out[O_ATT + e0 + idx]);
    __syncthreads();

    // binary search for K = max T with count(key >= T) >= KSEL
    unsigned lo = 0u, hi = 0xFFFFFFFFu;
    const int cbase = t * 16;            // blocked chunk, threads 0..249 active
    while (lo < hi) {
        unsigned mid = lo + ((hi - lo) >> 1) + 1u;
        if (t == 0) cnt = 0;
        __syncthreads();
        int c = 0;
        if (t < 250) {
#pragma unroll
            for (int q = 0; q < 16; ++q) c += (keys[cbase + q] >= mid) ? 1 : 0;
        }
        if (c) atomicAdd(&cnt, c);
        __syncthreads();
        int f = cnt;
        if (f >= KSEL) lo = mid; else hi = mid - 1u;
        __syncthreads();
    }
    const unsigned K = lo;
    const float v = dec_key(K);
    const unsigned khi = enc_key(v + DELTA);
    const unsigned klo = enc_key(v - DELTA);

    // in_cnt = #{key > khi}
    if (t == 0) cnt = 0;
    __syncthreads();
    {
        int c = 0;
        if (t < 250) {
#pragma unroll
            for (int q = 0; q < 16; ++q) c += (keys[cbase + q] > khi) ? 1 : 0;
        }
        if (c) atomicAdd(&cnt, c);
    }
    __syncthreads();
    if (t == 0) need[g] = KSEL - cnt;

    // classify and emit; boundary edges deferred to blist
    for (int idx = t; idx < EPG; idx += 256) {
        unsigned kk = keys[idx];
        int ge = e0 + idx;
        float a = dec_key(kk);
        if (kk > khi) {
            out[O_CEW + ge]  = a;
            out[O_SEW + ge]  = 0.0f;
            out[O_MASK + ge] = 1.0f;
            atomicAdd(&deg[ei[ge]], 1.0f);
            atomicAdd(&deg[ei[NE + ge]], 1.0f);
        } else if (kk < klo) {
            out[O_CEW + ge]  = 0.0f;
            out[O_SEW + ge]  = a;
            out[O_MASK + ge] = 0.0f;
        } else {
            int p = atomicAdd(&bcnt[g], 1);
            if (p < MAXB) blist[g * MAXB + p] = ge;
        }
    }
}

// ---------------- exact fp32 recompute of boundary edges ----------------
// j-split variant of the round-1 fp32 MLP: block = (graph, chunk, jt).
// 128 edges x 64 j-columns per block; partial sums go to attx8[edge][jt].
#define TE_  128
#define PADX 132
#define PADW 68

__global__ __launch_bounds__(256)
void repair_kernel(const float* __restrict__ emb, const int* __restrict__ ei,
                   const float* __restrict__ W1, const float* __restrict__ b1,
                   const float* __restrict__ W2,
                   const int* __restrict__ bcnt, const int* __restrict__ blist,
                   float* __restrict__ attx8)
{
    const int blk = blockIdx.x;        // g*(NRC*RJT) + ch*RJT + jt
    const int jt  = blk & 7;
    const int ch  = (blk >> 3) & (NRC - 1);
    const int g   = blk >> 6;
    const int bc  = min(bcnt[g], MAXB);
    if (ch * 128 >= bc) return;

    __shared__ __align__(16) float Xs[32 * PADX];   // 16.9 KB
    __shared__ __align__(16) float Ws[32 * PADW];   //  8.7 KB
    __shared__ int sidx[TE_], cidx[TE_];

    const int t = threadIdx.x;
    if (t < TE_) {
        int lid = ch * 128 + t;
        int lc  = min(lid, bc - 1);
        int e   = blist[g * MAXB + lc];
        sidx[t] = ei[e];
        cidx[t] = ei[NE + e];
    }
    __syncthreads();

    const int te = t & 15;     // edge group: edges te*8..te*8+7
    const int tj = t >> 4;     // j group: j jt*64 + tj*4..+3

    float acc[8][4];
#pragma unroll
    for (int a = 0; a < 8; ++a)
#pragma unroll
        for (int b = 0; b < 4; ++b) acc[a][b] = 0.0f;

    for (int kt = 0; kt < 8; ++kt) {
        __syncthreads();
        // stage X: 32 k x 128 e (gathered), float4 along k
#pragma unroll
        for (int i = 0; i < 4; ++i) {
            int flat = i * 256 + t;           // 0..1023
            int e  = flat >> 3;
            int k4 = flat & 7;
            int k  = kt * 32 + k4 * 4;
            const float* src;
            if (k < HID) src = emb + (long)sidx[e] * HID + k;
            else         src = emb + (long)cidx[e] * HID + (k - HID);
            float4 v = *(const float4*)src;
            int kl = k4 * 4;
            Xs[(kl + 0) * PADX + e] = v.x;
            Xs[(kl + 1) * PADX + e] = v.y;
            Xs[(kl + 2) * PADX + e] = v.z;
            Xs[(kl + 3) * PADX + e] = v.w;
        }
        // stage W1 tile: 32 k x 64 j (this block's jt slice)
#pragma unroll
        for (int i = 0; i < 2; ++i) {
            int flat = i * 256 + t;           // 0..511
            int kl = flat >> 4;
            int j4 = flat & 15;
            float4 v = *(const float4*)&W1[(kt * 32 + kl) * 512 + jt * 64 + j4 * 4];
            *(float4*)&Ws[kl * PADW + j4 * 4] = v;
        }
        __syncthreads();

#pragma unroll 4
        for (int kl = 0; kl < 32; ++kl) {
            float4 xa = *(const float4*)&Xs[kl * PADX + te * 8];
            float4 xb = *(const float4*)&Xs[kl * PADX + te * 8 + 4];
            float4 wa = *(const float4*)&Ws[kl * PADW + tj * 4];
            float xv[8] = {xa.x, xa.y, xa.z, xa.w, xb.x, xb.y, xb.z, xb.w};
            float wv[4] = {wa.x, wa.y, wa.z, wa.w};
#pragma unroll
            for (int a = 0; a < 8; ++a)
#pragma unroll
                for (int b = 0; b < 4; ++b)
                    acc[a][b] = fmaf(xv[a], wv[b], acc[a][b]);
        }
    }

    // epilogue: relu(+b1) * W2 over this block's 4 j's per thread
    const int jb = jt * 64 + tj * 4;
    float4 b1a = *(const float4*)&b1[jb];
    float4 w2a = *(const float4*)&W2[jb];
    float bv[4] = {b1a.x, b1a.y, b1a.z, b1a.w};
    float wv[4] = {w2a.x, w2a.y, w2a.z, w2a.w};
    float attp[8];
#pragma unroll
    for (int a = 0; a < 8; ++a) {
        float s = 0.0f;
#pragma unroll
        for (int b = 0; b < 4; ++b)
            s = fmaf(fmaxf(acc[a][b] + bv[b], 0.0f), wv[b], s);
        attp[a] = s;
    }

    // reduce across the 16 tj groups
    __syncthreads();
    float* red = Xs;   // 16*136 = 2176 floats, fits
#pragma unroll
    for (int a = 0; a < 8; ++a) red[tj * 136 + te * 8 + a] = attp[a];
    __syncthreads();
    if (t < TE_ && ch * 128 + t < bc) {
        float s = 0.0f;
#pragma unroll
        for (int q = 0; q < 16; ++q) s += red[q * 136 + t];
        attx8[(g * MAXB + ch * 128 + t) * RJT + jt] = s;
    }
}

// ---------------- exact selection among boundary edges ----------------
__global__ __launch_bounds__(256)
void select_kernel(const int* __restrict__ ei, const int* __restrict__ bcnt,
                   const int* __restrict__ need, const int* __restrict__ blist,
                   const float* __restrict__ attx8, const float* __restrict__ b2,
                   float* __restrict__ out, float* __restrict__ deg)
{
    __shared__ float sa[MAXB];
    __shared__ int   si[MAXB];
    const int g = blockIdx.x;
    const int t = threadIdx.x;
    const int b = min(bcnt[g], MAXB);
    const int n = need[g];
    const float bias2 = b2[0];

    for (int i = t; i < b; i += 256) {
        float s = bias2;
#pragma unroll
        for (int jt = 0; jt < RJT; ++jt)
            s += attx8[(g * MAXB + i) * RJT + jt];
        sa[i] = s;
        si[i] = blist[g * MAXB + i];
    }
    __syncthreads();

    for (int i = t; i < b; i += 256) {
        float ai = sa[i];
        int   ii = si[i];
        int rank = 0;
        for (int j = 0; j < b; ++j)
            rank += (sa[j] > ai || (sa[j] == ai && si[j] < ii)) ? 1 : 0;
        bool flag = rank < n;
        out[O_CEW + ii]  = flag ? ai : 0.0f;
        out[O_SEW + ii]  = flag ? 0.0f : ai;
        out[O_MASK + ii] = flag ? 1.0f : 0.0f;
        if (flag) {
            atomicAdd(&deg[ei[ii]], 1.0f);
            atomicAdd(&deg[ei[NE + ii]], 1.0f);
        }
    }
}

// ---------------- node relabel: global prefix scan over node_mask ----------------
__global__ __launch_bounds__(256)
void scanA(const float* __restrict__ deg, int* __restrict__ partials)
{
    __shared__ int s[256];
    int t = threadIdx.x;
    int n = blockIdx.x * 256 + t;
    int m = (n < NNODES && deg[n] > 0.5f) ? 1 : 0;
    s[t] = m;
    __syncthreads();
    for (int off = 128; off > 0; off >>= 1) {
        if (t < off) s[t] += s[t + off];
        __syncthreads();
    }
    if (t == 0) partials[blockIdx.x] = s[0];
}

__global__ __launch_bounds__(256)
void scanB(int* __restrict__ partials)
{
    __shared__ int s[256];
    int t = threadIdx.x;
    int v = (t < NB_SCAN) ? partials[t] : 0;
    s[t] = v;
    __syncthreads();
    for (int off = 1; off < 256; off <<= 1) {
        int x = (t >= off) ? s[t - off] : 0;
        __syncthreads();
        s[t] += x;
        __syncthreads();
    }
    if (t < NB_SCAN) partials[t] = s[t] - v;   // exclusive prefix
}

__global__ __launch_bounds__(256)
void scanC(float* __restrict__ deg_nm, const int* __restrict__ partials,
           int* __restrict__ newid)
{
    __shared__ int s[256];
    int t = threadIdx.x;
    int b = blockIdx.x;
    int n = b * 256 + t;
    int m = (n < NNODES && deg_nm[n] > 0.5f) ? 1 : 0;
    s[t] = m;
    __syncthreads();
    for (int off = 1; off < 256; off <<= 1) {
        int x = (t >= off) ? s[t - off] : 0;
        __syncthreads();
        s[t] += x;
        __syncthreads();
    }
    if (n < NNODES) {
        newid[n]  = partials[b] + s[t] - 1;   // cumsum(mask)-1
        deg_nm[n] = m ? 1.0f : 0.0f;          // finalize node_mask output
    }
}

__global__ __launch_bounds__(256)
void edges_final(const int* __restrict__ ei, const int* __restrict__ newid,
                 float* __restrict__ out)
{
    int e = blockIdx.x * 256 + threadIdx.x;
    if (e >= NE) return;
    bool flag = out[O_MASK + e] > 0.5f;
    int row = ei[e];
    int col = ei[NE + e];
    out[O_CEI + e]      = flag ? (float)newid[row] : -1.0f;
    out[O_CEI + NE + e] = flag ? (float)newid[col] : -1.0f;
}

__global__ __launch_bounds__(256)
void causal_x_kernel(const float* __restrict__ emb, const float* __restrict__ nm,
                     float* __restrict__ out)
{
    int i4 = blockIdx.x * 256 + threadIdx.x;       // float4 index
    if (i4 >= NNODES * HID / 4) return;
    int n = i4 >> 5;                               // 32 float4 per node
    float4 v = ((const float4*)emb)[i4];
    if (!(nm[n] > 0.5f)) v = make_float4(0.0f, 0.0f, 0.0f, 0.0f);
    ((float4*)(out + O_CX))[i4] = v;
}

extern "C" void kernel_launch(void* const* d_in, const int* in_sizes, int n_in,
                              void* d_out, int out_size, void* d_ws, size_t ws_size,
                              hipStream_t stream)
{
    const float* emb = (const float*)d_in[0];
    const int*   ei  = (const int*)d_in[1];
    // d_in[2] = node_batch (implied by edge layout; unused)
    const float* W1  = (const float*)d_in[3];
    const float* b1  = (const float*)d_in[4];
    const float* W2  = (const float*)d_in[5];
    const float* b2  = (const float*)d_in[6];
    float* out = (float*)d_out;

    char* wsb = (char*)d_ws;
    int*   newid    = (int*)wsb;                          // 200000 B
    int*   partials = (int*)(wsb + 200704);
    int*   bcnt     = (int*)(wsb + 201728);               // NG ints
    int*   need     = (int*)(wsb + 202752);               // NG ints
    int*   blist    = (int*)(wsb + 203776);               // NG*MAXB ints (400 KB)
    float* attx8    = (float*)(wsb + 203776 + NG*MAXB*4); // NG*MAXB*RJT floats (3.3 MB)
    unsigned short* embb = (unsigned short*)(wsb + 203776 + NG*MAXB*4 + NG*MAXB*RJT*4);
    unsigned short* w1p  = embb + NNODES * HID;           // 131072 bf16
    float* deg = out + O_NMASK;                           // node_mask region as deg accum

    hipMemsetAsync(deg, 0, NNODES * sizeof(float), stream);
    hipMemsetAsync(bcnt, 0, NG * sizeof(int), stream);

    tobf_kernel<<<NNODES * HID / 4 / 256, 256, 0, stream>>>(emb, embb);
    pack_w1_kernel<<<512, 256, 0, stream>>>(W1, w1p);
    att4_kernel<<<(NE + 255) / 256, 256, 0, stream>>>(embb, w1p, ei, b1, W2, b2, out);
    topk4_kernel<<<NG, 256, 0, stream>>>(ei, out, deg, bcnt, need, blist);
    repair_kernel<<<NG * NRC * RJT, 256, 0, stream>>>(emb, ei, W1, b1, W2,
                                                      bcnt, blist, attx8);
    select_kernel<<<NG, 256, 0, stream>>>(ei, bcnt, need, blist, attx8, b2, out, deg);
    scanA<<<NB_SCAN, 256, 0, stream>>>(deg, partials);
    scanB<<<1, 256, 0, stream>>>(partials);
    scanC<<<NB_SCAN, 256, 0, stream>>>(deg, partials, newid);
    edges_final<<<(NE + 255) / 256, 256, 0, stream>>>(ei, newid, out);
    causal_x_kernel<<<(NNODES * HID / 4 + 255) / 256, 256, 0, stream>>>(emb, deg, out);
}

// Round 6
// 531.609 us; speedup vs baseline: 2.5824x; 1.0558x over previous
//
#include <hip/hip_runtime.h>
#include <hip/hip_bf16.h>

// Problem constants (fixed by setup_inputs)
#define NG      100
#define NPG     500
#define EPG     4000
#define HID     128
#define NNODES  (NG*NPG)     // 50000
#define NE      (NG*EPG)     // 400000
#define KSEL    2000         // ceil(0.5*4000)
#define NB_SCAN ((NNODES + 255) / 256)   // 196

#define MAXB    1024         // boundary-list capacity per graph (expect ~140)
#define NRC     8            // repair chunks per graph (MAXB/128)
#define RJT     8            // repair j-tiles (512/64)
#define DELTA   0.03125f     // screening margin (~2x observed bf16 att max err)

// Output layout (floats, concatenated in reference return order)
#define O_ATT   0
#define O_CEW   (NE)
#define O_SEW   (2*NE)
#define O_MASK  (3*NE)
#define O_CEI   (4*NE)            // 2*NE entries: new_row then new_col
#define O_NMASK (6*NE)            // NNODES entries
#define O_CX    (6*NE + NNODES)   // NNODES*HID entries

typedef __attribute__((ext_vector_type(8))) short  short8;
typedef __attribute__((ext_vector_type(8))) __bf16 bf16x8;
typedef __attribute__((ext_vector_type(4))) float  f32x4;

#define MFMA16(a,b,c) __builtin_amdgcn_mfma_f32_16x16x32_bf16( \
    __builtin_bit_cast(bf16x8,(a)), __builtin_bit_cast(bf16x8,(b)), (c), 0, 0, 0)

#define GLOAD_LDS16(g, l) __builtin_amdgcn_global_load_lds( \
    (const __attribute__((address_space(1))) unsigned int*)(g), \
    (__attribute__((address_space(3)))       unsigned int*)(l), 16, 0, 0)

__device__ __forceinline__ unsigned short tobf(float x) {
    __hip_bfloat16 hb = __float2bfloat16(x);
    return *(unsigned short*)&hb;
}

// ---------------- preprocessing: emb -> bf16 (RNE) ----------------
__global__ __launch_bounds__(256)
void tobf_kernel(const float* __restrict__ emb, unsigned short* __restrict__ eb)
{
    int i = blockIdx.x * 256 + threadIdx.x;          // float4 index, 1.6M total
    float4 v = ((const float4*)emb)[i];
    ushort4 h;
    h.x = tobf(v.x); h.y = tobf(v.y); h.z = tobf(v.z); h.w = tobf(v.w);
    ((ushort4*)eb)[i] = h;
}

// ---------------- preprocessing: pack W1 bf16 into B-fragment order -------
// 16x16x32 operand layout: fragment col = lane&15, k = (lane>>4)*8 + i.
// Packed idx = g*512 + lane*8 + i with g = (kc*8 + jo)*4 + jsub;
//   j = jo*64 + jsub*16 + (lane&15);  k = kc*32 + (lane>>4)*8 + i
__global__ __launch_bounds__(256)
void pack_w1_kernel(const float* __restrict__ W1, unsigned short* __restrict__ ph)
{
    int idx  = blockIdx.x * 256 + threadIdx.x;       // 131072 total
    int i    = idx & 7;
    int lane = (idx >> 3) & 63;
    int g    = idx >> 9;
    int jsub = g & 3;
    int rem  = g >> 2;
    int jo   = rem & 7;
    int kc   = rem >> 3;                             // 0..7
    int j = jo * 64 + jsub * 16 + (lane & 15);
    int k = kc * 32 + (lane >> 4) * 8 + i;
    ph[idx] = tobf(W1[k * 512 + j]);
}

// ---------------- screening GEMM: bf16 MFMA, double-buffered B ------------
// Block: 256 threads = 4 waves; 64 edges/wave (4 M-tiles of 16) -> 256/block.
// Segment = one jo (64 j-cols) x full K=256: 32 chunks of 1 KB = 32 KB.
// 8 segments, double-buffered (2 x 32 KB LDS), prefetch issued pre-compute.
__global__ __launch_bounds__(256)
void att5_kernel(const unsigned short* __restrict__ embb,
                 const unsigned short* __restrict__ w1p,
                 const int* __restrict__ ei,
                 const float* __restrict__ b1,
                 const float* __restrict__ W2,
                 const float* __restrict__ b2,
                 float* __restrict__ out)
{
    // 2 buffers x 32 chunks x 512 bf16; chunk c = kc*4 + jsub, kc in [0,8)
    __shared__ __align__(16) unsigned short ldsB[32768];   // 64 KB

    const int t    = threadIdx.x;
    const int w    = t >> 6;        // wave 0..3
    const int lane = t & 63;
    const int r16  = lane & 15;
    const int quad = lane >> 4;

    const int e_base = blockIdx.x * 256 + w * 64;
    int sb[4], db[4];
#pragma unroll
    for (int mt = 0; mt < 4; ++mt) {
        int e = min(e_base + mt * 16 + r16, NE - 1);
        sb[mt] = ei[e] << 8;                  // byte base, 256 B per node row
        db[mt] = ei[NE + e] << 8;
    }

    const char* eb = (const char*)embb;

    float attP[4][4];
#pragma unroll
    for (int mt = 0; mt < 4; ++mt)
#pragma unroll
        for (int rg = 0; rg < 4; ++rg) attP[mt][rg] = 0.0f;

    // stage segment jo into buffer buf: wave w stages chunks w*8..w*8+7
#define STAGE(jo_, buf_)                                                     \
    {                                                                        \
        _Pragma("unroll")                                                    \
        for (int cc = 0; cc < 8; ++cc) {                                     \
            int c    = w * 8 + cc;                                           \
            int kc   = c >> 2;                                               \
            int jsub = c & 3;                                                \
            int g    = (kc * 8 + (jo_)) * 4 + jsub;                          \
            GLOAD_LDS16(w1p + g * 512 + lane * 8,                            \
                        ldsB + (buf_) * 16384 + c * 512);                    \
        }                                                                    \
    }

    STAGE(0, 0);
    __syncthreads();

    for (int jo = 0; jo < 8; ++jo) {
        const int cur = jo & 1;
        if (jo < 7) STAGE(jo + 1, cur ^ 1);   // prefetch next segment early

        f32x4 acc[4][4];   // [mt][jsub]
#pragma unroll
        for (int mt = 0; mt < 4; ++mt)
#pragma unroll
            for (int js = 0; js < 4; ++js) acc[mt][js] = f32x4{};

#pragma unroll
        for (int kc = 0; kc < 8; ++kc) {
            const int off = (kc & 3) * 64 + quad * 16;   // bytes in half-row
            short8 A[4];
#pragma unroll
            for (int mt = 0; mt < 4; ++mt)
                A[mt] = *(const short8*)(eb + ((kc >= 4) ? db[mt] : sb[mt]) + off);
#pragma unroll
            for (int jsub = 0; jsub < 4; ++jsub) {
                short8 B = *(const short8*)(ldsB + cur * 16384 +
                                            (kc * 4 + jsub) * 512 + lane * 8);
#pragma unroll
                for (int mt = 0; mt < 4; ++mt)
                    acc[mt][jsub] = MFMA16(A[mt], B, acc[mt][jsub]);
            }
        }

        // epilogue: h = relu(y + b1[j]); attP += h * W2[j]   (j col = r16)
#pragma unroll
        for (int jsub = 0; jsub < 4; ++jsub) {
            const int j = jo * 64 + jsub * 16 + r16;
            const float b1v = b1[j], w2v = W2[j];
#pragma unroll
            for (int mt = 0; mt < 4; ++mt)
#pragma unroll
                for (int rg = 0; rg < 4; ++rg)
                    attP[mt][rg] += fmaxf(acc[mt][jsub][rg] + b1v, 0.0f) * w2v;
        }
        __syncthreads();   // prefetch landed + all reads of cur done
    }
#undef STAGE

    // sum over the 16 j-columns: butterfly over low 4 lane bits
#pragma unroll
    for (int mt = 0; mt < 4; ++mt)
#pragma unroll
        for (int rg = 0; rg < 4; ++rg) {
            float v = attP[mt][rg];
#pragma unroll
            for (int msk = 1; msk <= 8; msk <<= 1) v += __shfl_xor(v, msk, 64);
            attP[mt][rg] = v;
        }

    const float bias2 = b2[0];
    if (r16 < 4) {
#pragma unroll
        for (int mt = 0; mt < 4; ++mt) {
            const int row = quad * 4 + r16;    // C/D row = (lane>>4)*4 + reg
            const int e   = e_base + mt * 16 + row;
            if (e < NE) out[O_ATT + e] = attP[mt][r16] + bias2;
        }
    }
}

// ---------------- per-graph top-k screening ----------------
__device__ __forceinline__ unsigned enc_key(float f) {
    unsigned u = __float_as_uint(f);
    return (u & 0x80000000u) ? ~u : (u | 0x80000000u);
}
__device__ __forceinline__ float dec_key(unsigned k) {
    unsigned u = (k & 0x80000000u) ? (k ^ 0x80000000u) : ~k;
    return __uint_as_float(u);
}

__global__ __launch_bounds__(256)
void topk4_kernel(const int* __restrict__ ei, float* __restrict__ out,
                  float* __restrict__ deg, int* __restrict__ bcnt,
                  int* __restrict__ need, int* __restrict__ blist)
{
    __shared__ int cnt;

    const int g  = blockIdx.x;
    const int t  = threadIdx.x;
    const int e0 = g * EPG;
    const int cbase = t * 16;            // blocked chunk, threads 0..249 active
    const bool act = (t < 250);

    // keys live in registers: 16 per thread, loaded as 4 x float4
    unsigned kreg[16];
    if (act) {
#pragma unroll
        for (int q4 = 0; q4 < 4; ++q4) {
            float4 v = *(const float4*)&out[O_ATT + e0 + cbase + q4 * 4];
            kreg[q4 * 4 + 0] = enc_key(v.x);
            kreg[q4 * 4 + 1] = enc_key(v.y);
            kreg[q4 * 4 + 2] = enc_key(v.z);
            kreg[q4 * 4 + 3] = enc_key(v.w);
        }
    }

    // binary search for K = max T with count(key >= T) >= KSEL
    unsigned lo = 0u, hi = 0xFFFFFFFFu;
    while (lo < hi) {
        unsigned mid = lo + ((hi - lo) >> 1) + 1u;
        if (t == 0) cnt = 0;
        __syncthreads();
        int c = 0;
        if (act) {
#pragma unroll
            for (int q = 0; q < 16; ++q) c += (kreg[q] >= mid) ? 1 : 0;
        }
        if (c) atomicAdd(&cnt, c);
        __syncthreads();
        int f = cnt;
        if (f >= KSEL) lo = mid; else hi = mid - 1u;
        __syncthreads();
    }
    const unsigned K = lo;
    const float v = dec_key(K);
    const unsigned khi = enc_key(v + DELTA);
    const unsigned klo = enc_key(v - DELTA);

    // in_cnt = #{key > khi}
    if (t == 0) cnt = 0;
    __syncthreads();
    {
        int c = 0;
        if (act) {
#pragma unroll
            for (int q = 0; q < 16; ++q) c += (kreg[q] > khi) ? 1 : 0;
        }
        if (c) atomicAdd(&cnt, c);
    }
    __syncthreads();
    if (t == 0) need[g] = KSEL - cnt;

    // classify own chunk; boundary edges deferred to blist
    if (act) {
#pragma unroll
        for (int q = 0; q < 16; ++q) {
            unsigned kk = kreg[q];
            int ge = e0 + cbase + q;
            float a = dec_key(kk);
            if (kk > khi) {
                out[O_CEW + ge]  = a;
                out[O_SEW + ge]  = 0.0f;
                out[O_MASK + ge] = 1.0f;
                atomicAdd(&deg[ei[ge]], 1.0f);
                atomicAdd(&deg[ei[NE + ge]], 1.0f);
            } else if (kk < klo) {
                out[O_CEW + ge]  = 0.0f;
                out[O_SEW + ge]  = a;
                out[O_MASK + ge] = 0.0f;
            } else {
                int p = atomicAdd(&bcnt[g], 1);
                if (p < MAXB) blist[g * MAXB + p] = ge;
            }
        }
    }
}

// ---------------- exact fp32 recompute of boundary edges ----------------
// j-split variant of the round-1 fp32 MLP: block = (graph, chunk, jt).
// 128 edges x 64 j-columns per block; partial sums go to attx8[edge][jt].
#define TE_  128
#define PADX 132
#define PADW 68

__global__ __launch_bounds__(256)
void repair_kernel(const float* __restrict__ emb, const int* __restrict__ ei,
                   const float* __restrict__ W1, const float* __restrict__ b1,
                   const float* __restrict__ W2,
                   const int* __restrict__ bcnt, const int* __restrict__ blist,
                   float* __restrict__ attx8)
{
    const int blk = blockIdx.x;        // g*(NRC*RJT) + ch*RJT + jt
    const int jt  = blk & 7;
    const int ch  = (blk >> 3) & (NRC - 1);
    const int g   = blk >> 6;
    const int bc  = min(bcnt[g], MAXB);
    if (ch * 128 >= bc) return;

    __shared__ __align__(16) float Xs[32 * PADX];   // 16.9 KB
    __shared__ __align__(16) float Ws[32 * PADW];   //  8.7 KB
    __shared__ int sidx[TE_], cidx[TE_];

    const int t = threadIdx.x;
    if (t < TE_) {
        int lid = ch * 128 + t;
        int lc  = min(lid, bc - 1);
        int e   = blist[g * MAXB + lc];
        sidx[t] = ei[e];
        cidx[t] = ei[NE + e];
    }
    __syncthreads();

    const int te = t & 15;     // edge group: edges te*8..te*8+7
    const int tj = t >> 4;     // j group: j jt*64 + tj*4..+3

    float acc[8][4];
#pragma unroll
    for (int a = 0; a < 8; ++a)
#pragma unroll
        for (int b = 0; b < 4; ++b) acc[a][b] = 0.0f;

    for (int kt = 0; kt < 8; ++kt) {
        __syncthreads();
        // stage X: 32 k x 128 e (gathered), float4 along k
#pragma unroll
        for (int i = 0; i < 4; ++i) {
            int flat = i * 256 + t;           // 0..1023
            int e  = flat >> 3;
            int k4 = flat & 7;
            int k  = kt * 32 + k4 * 4;
            const float* src;
            if (k < HID) src = emb + (long)sidx[e] * HID + k;
            else         src = emb + (long)cidx[e] * HID + (k - HID);
            float4 v = *(const float4*)src;
            int kl = k4 * 4;
            Xs[(kl + 0) * PADX + e] = v.x;
            Xs[(kl + 1) * PADX + e] = v.y;
            Xs[(kl + 2) * PADX + e] = v.z;
            Xs[(kl + 3) * PADX + e] = v.w;
        }
        // stage W1 tile: 32 k x 64 j (this block's jt slice)
#pragma unroll
        for (int i = 0; i < 2; ++i) {
            int flat = i * 256 + t;           // 0..511
            int kl = flat >> 4;
            int j4 = flat & 15;
            float4 v = *(const float4*)&W1[(kt * 32 + kl) * 512 + jt * 64 + j4 * 4];
            *(float4*)&Ws[kl * PADW + j4 * 4] = v;
        }
        __syncthreads();

#pragma unroll 4
        for (int kl = 0; kl < 32; ++kl) {
            float4 xa = *(const float4*)&Xs[kl * PADX + te * 8];
            float4 xb = *(const float4*)&Xs[kl * PADX + te * 8 + 4];
            float4 wa = *(const float4*)&Ws[kl * PADW + tj * 4];
            float xv[8] = {xa.x, xa.y, xa.z, xa.w, xb.x, xb.y, xb.z, xb.w};
            float wv[4] = {wa.x, wa.y, wa.z, wa.w};
#pragma unroll
            for (int a = 0; a < 8; ++a)
#pragma unroll
                for (int b = 0; b < 4; ++b)
                    acc[a][b] = fmaf(xv[a], wv[b], acc[a][b]);
        }
    }

    // epilogue: relu(+b1) * W2 over this block's 4 j's per thread
    const int jb = jt * 64 + tj * 4;
    float4 b1a = *(const float4*)&b1[jb];
    float4 w2a = *(const float4*)&W2[jb];
    float bv[4] = {b1a.x, b1a.y, b1a.z, b1a.w};
    float wv[4] = {w2a.x, w2a.y, w2a.z, w2a.w};
    float attp[8];
#pragma unroll
    for (int a = 0; a < 8; ++a) {
        float s = 0.0f;
#pragma unroll
        for (int b = 0; b < 4; ++b)
            s = fmaf(fmaxf(acc[a][b] + bv[b], 0.0f), wv[b], s);
        attp[a] = s;
    }

    // reduce across the 16 tj groups
    __syncthreads();
    float* red = Xs;   // 16*136 = 2176 floats, fits
#pragma unroll
    for (int a = 0; a < 8; ++a) red[tj * 136 + te * 8 + a] = attp[a];
    __syncthreads();
    if (t < TE_ && ch * 128 + t < bc) {
        float s = 0.0f;
#pragma unroll
        for (int q = 0; q < 16; ++q) s += red[q * 136 + t];
        attx8[(g * MAXB + ch * 128 + t) * RJT + jt] = s;
    }
}

// ---------------- exact selection among boundary edges ----------------
__global__ __launch_bounds__(256)
void select_kernel(const int* __restrict__ ei, const int* __restrict__ bcnt,
                   const int* __restrict__ need, const int* __restrict__ blist,
                   const float* __restrict__ attx8, const float* __restrict__ b2,
                   float* __restrict__ out, float* __restrict__ deg)
{
    __shared__ float sa[MAXB];
    __shared__ int   si[MAXB];
    const int g = blockIdx.x;
    const int t = threadIdx.x;
    const int b = min(bcnt[g], MAXB);
    const int n = need[g];
    const float bias2 = b2[0];

    for (int i = t; i < b; i += 256) {
        float s = bias2;
#pragma unroll
        for (int jt = 0; jt < RJT; ++jt)
            s += attx8[(g * MAXB + i) * RJT + jt];
        sa[i] = s;
        si[i] = blist[g * MAXB + i];
    }
    __syncthreads();

    for (int i = t; i < b; i += 256) {
        float ai = sa[i];
        int   ii = si[i];
        int rank = 0;
        for (int j = 0; j < b; ++j)
            rank += (sa[j] > ai || (sa[j] == ai && si[j] < ii)) ? 1 : 0;
        bool flag = rank < n;
        out[O_CEW + ii]  = flag ? ai : 0.0f;
        out[O_SEW + ii]  = flag ? 0.0f : ai;
        out[O_MASK + ii] = flag ? 1.0f : 0.0f;
        if (flag) {
            atomicAdd(&deg[ei[ii]], 1.0f);
            atomicAdd(&deg[ei[NE + ii]], 1.0f);
        }
    }
}

// ---------------- node relabel: global prefix scan over node_mask ----------------
__global__ __launch_bounds__(256)
void scanA(const float* __restrict__ deg, int* __restrict__ partials)
{
    __shared__ int s[256];
    int t = threadIdx.x;
    int n = blockIdx.x * 256 + t;
    int m = (n < NNODES && deg[n] > 0.5f) ? 1 : 0;
    s[t] = m;
    __syncthreads();
    for (int off = 128; off > 0; off >>= 1) {
        if (t < off) s[t] += s[t + off];
        __syncthreads();
    }
    if (t == 0) partials[blockIdx.x] = s[0];
}

__global__ __launch_bounds__(256)
void scanB(int* __restrict__ partials)
{
    __shared__ int s[256];
    int t = threadIdx.x;
    int v = (t < NB_SCAN) ? partials[t] : 0;
    s[t] = v;
    __syncthreads();
    for (int off = 1; off < 256; off <<= 1) {
        int x = (t >= off) ? s[t - off] : 0;
        __syncthreads();
        s[t] += x;
        __syncthreads();
    }
    if (t < NB_SCAN) partials[t] = s[t] - v;   // exclusive prefix
}

__global__ __launch_bounds__(256)
void scanC(float* __restrict__ deg_nm, const int* __restrict__ partials,
           int* __restrict__ newid)
{
    __shared__ int s[256];
    int t = threadIdx.x;
    int b = blockIdx.x;
    int n = b * 256 + t;
    int m = (n < NNODES && deg_nm[n] > 0.5f) ? 1 : 0;
    s[t] = m;
    __syncthreads();
    for (int off = 1; off < 256; off <<= 1) {
        int x = (t >= off) ? s[t - off] : 0;
        __syncthreads();
        s[t] += x;
        __syncthreads();
    }
    if (n < NNODES) {
        newid[n]  = partials[b] + s[t] - 1;   // cumsum(mask)-1
        deg_nm[n] = m ? 1.0f : 0.0f;          // finalize node_mask output
    }
}

__global__ __launch_bounds__(256)
void edges_final(const int* __restrict__ ei, const int* __restrict__ newid,
                 float* __restrict__ out)
{
    int e = blockIdx.x * 256 + threadIdx.x;
    if (e >= NE) return;
    bool flag = out[O_MASK + e] > 0.5f;
    int row = ei[e];
    int col = ei[NE + e];
    out[O_CEI + e]      = flag ? (float)newid[row] : -1.0f;
    out[O_CEI + NE + e] = flag ? (float)newid[col] : -1.0f;
}

__global__ __launch_bounds__(256)
void causal_x_kernel(const float* __restrict__ emb, const float* __restrict__ nm,
                     float* __restrict__ out)
{
    int i4 = blockIdx.x * 256 + threadIdx.x;       // float4 index
    if (i4 >= NNODES * HID / 4) return;
    int n = i4 >> 5;                               // 32 float4 per node
    float4 v = ((const float4*)emb)[i4];
    if (!(nm[n] > 0.5f)) v = make_float4(0.0f, 0.0f, 0.0f, 0.0f);
    ((float4*)(out + O_CX))[i4] = v;
}

extern "C" void kernel_launch(void* const* d_in, const int* in_sizes, int n_in,
                              void* d_out, int out_size, void* d_ws, size_t ws_size,
                              hipStream_t stream)
{
    const float* emb = (const float*)d_in[0];
    const int*   ei  = (const int*)d_in[1];
    // d_in[2] = node_batch (implied by edge layout; unused)
    const float* W1  = (const float*)d_in[3];
    const float* b1  = (const float*)d_in[4];
    const float* W2  = (const float*)d_in[5];
    const float* b2  = (const float*)d_in[6];
    float* out = (float*)d_out;

    char* wsb = (char*)d_ws;
    int*   newid    = (int*)wsb;                          // 200000 B
    int*   partials = (int*)(wsb + 200704);
    int*   bcnt     = (int*)(wsb + 201728);               // NG ints
    int*   need     = (int*)(wsb + 202752);               // NG ints
    int*   blist    = (int*)(wsb + 203776);               // NG*MAXB ints (400 KB)
    float* attx8    = (float*)(wsb + 203776 + NG*MAXB*4); // NG*MAXB*RJT floats (3.3 MB)
    unsigned short* embb = (unsigned short*)(wsb + 203776 + NG*MAXB*4 + NG*MAXB*RJT*4);
    unsigned short* w1p  = embb + NNODES * HID;           // 131072 bf16
    float* deg = out + O_NMASK;                           // node_mask region as deg accum

    hipMemsetAsync(deg, 0, NNODES * sizeof(float), stream);
    hipMemsetAsync(bcnt, 0, NG * sizeof(int), stream);

    tobf_kernel<<<NNODES * HID / 4 / 256, 256, 0, stream>>>(emb, embb);
    pack_w1_kernel<<<512, 256, 0, stream>>>(W1, w1p);
    att5_kernel<<<(NE + 255) / 256, 256, 0, stream>>>(embb, w1p, ei, b1, W2, b2, out);
    topk4_kernel<<<NG, 256, 0, stream>>>(ei, out, deg, bcnt, need, blist);
    repair_kernel<<<NG * NRC * RJT, 256, 0, stream>>>(emb, ei, W1, b1, W2,
                                                      bcnt, blist, attx8);
    select_kernel<<<NG, 256, 0, stream>>>(ei, bcnt, need, blist, attx8, b2, out, deg);
    scanA<<<NB_SCAN, 256, 0, stream>>>(deg, partials);
    scanB<<<1, 256, 0, stream>>>(partials);
    scanC<<<NB_SCAN, 256, 0, stream>>>(deg, partials, newid);
    edges_final<<<(NE + 255) / 256, 256, 0, stream>>>(ei, newid, out);
    causal_x_kernel<<<(NNODES * HID / 4 + 255) / 256, 256, 0, stream>>>(emb, deg, out);
}

// Round 7
// 455.614 us; speedup vs baseline: 3.0131x; 1.1668x over previous
//
#include <hip/hip_runtime.h>
#include <hip/hip_bf16.h>

// Problem constants (fixed by setup_inputs)
#define NG      100
#define NPG     500
#define EPG     4000
#define HID     128
#define NNODES  (NG*NPG)     // 50000
#define NE      (NG*EPG)     // 400000
#define KSEL    2000         // ceil(0.5*4000)
#define NB_SCAN ((NNODES + 255) / 256)   // 196

#define MAXB    1024         // boundary-list capacity per graph (expect ~140)
#define NRC     8            // repair chunks per graph (MAXB/128)
#define RJT     8            // repair j-tiles (512/64)
#define DELTA   0.03125f     // screening margin (~2x observed bf16 att max err)

// Output layout (floats, concatenated in reference return order)
#define O_ATT   0
#define O_CEW   (NE)
#define O_SEW   (2*NE)
#define O_MASK  (3*NE)
#define O_CEI   (4*NE)            // 2*NE entries: new_row then new_col
#define O_NMASK (6*NE)            // NNODES entries
#define O_CX    (6*NE + NNODES)   // NNODES*HID entries

typedef __attribute__((ext_vector_type(8))) short  short8;
typedef __attribute__((ext_vector_type(8))) __bf16 bf16x8;
typedef __attribute__((ext_vector_type(4))) float  f32x4;

#define MFMA16(a,b,c) __builtin_amdgcn_mfma_f32_16x16x32_bf16( \
    __builtin_bit_cast(bf16x8,(a)), __builtin_bit_cast(bf16x8,(b)), (c), 0, 0, 0)

#define GLOAD_LDS16(g, l) __builtin_amdgcn_global_load_lds( \
    (const __attribute__((address_space(1))) unsigned int*)(g), \
    (__attribute__((address_space(3)))       unsigned int*)(l), 16, 0, 0)

__device__ __forceinline__ unsigned short tobf(float x) {
    __hip_bfloat16 hb = __float2bfloat16(x);
    return *(unsigned short*)&hb;
}

// ---------------- fused preprocessing ----------------
// blocks [0,6250): emb -> bf16 (RNE), float4 granularity
// blocks [6250,6762): pack W1 bf16 into B-fragment order
//   16x16x32 operand layout: fragment col = lane&15, k = (lane>>4)*8 + i.
//   Packed idx = g*512 + lane*8 + i with g = (kc*8 + jo)*4 + jsub;
//   j = jo*64 + jsub*16 + (lane&15);  k = kc*32 + (lane>>4)*8 + i
// blocks [6762,6811): zero deg
// block  6811: zero bcnt
#define PREP_TOBF 6250
#define PREP_PACK 512
#define PREP_DEG  49
#define PREP_GRID (PREP_TOBF + PREP_PACK + PREP_DEG + 1)

__global__ __launch_bounds__(256)
void prep_kernel(const float* __restrict__ emb, const float* __restrict__ W1,
                 unsigned short* __restrict__ eb, unsigned short* __restrict__ ph,
                 float* __restrict__ deg, int* __restrict__ bcnt)
{
    const int blk = blockIdx.x;
    const int t   = threadIdx.x;
    if (blk < PREP_TOBF) {
        int i = blk * 256 + t;                       // float4 index, 1.6M total
        float4 v = ((const float4*)emb)[i];
        ushort4 h;
        h.x = tobf(v.x); h.y = tobf(v.y); h.z = tobf(v.z); h.w = tobf(v.w);
        ((ushort4*)eb)[i] = h;
    } else if (blk < PREP_TOBF + PREP_PACK) {
        int idx  = (blk - PREP_TOBF) * 256 + t;      // 131072 total
        int i    = idx & 7;
        int lane = (idx >> 3) & 63;
        int g    = idx >> 9;
        int jsub = g & 3;
        int rem  = g >> 2;
        int jo   = rem & 7;
        int kc   = rem >> 3;                         // 0..7
        int j = jo * 64 + jsub * 16 + (lane & 15);
        int k = kc * 32 + (lane >> 4) * 8 + i;
        ph[idx] = tobf(W1[k * 512 + j]);
    } else if (blk < PREP_TOBF + PREP_PACK + PREP_DEG) {
        int i4 = (blk - PREP_TOBF - PREP_PACK) * 256 + t;
        if (i4 < NNODES / 4) ((float4*)deg)[i4] = make_float4(0.f, 0.f, 0.f, 0.f);
    } else {
        if (t < NG) bcnt[t] = 0;
    }
}

// ---------------- screening GEMM: bf16 MFMA, double-buffered B ------------
// Block: 256 threads = 4 waves; 64 edges/wave (4 M-tiles of 16) -> 256/block.
// Segment = one jo (64 j-cols) x full K=256: 32 chunks of 1 KB = 32 KB.
// 8 segments, double-buffered (2 x 32 KB LDS), prefetch issued pre-compute.
__global__ __launch_bounds__(256)
void att5_kernel(const unsigned short* __restrict__ embb,
                 const unsigned short* __restrict__ w1p,
                 const int* __restrict__ ei,
                 const float* __restrict__ b1,
                 const float* __restrict__ W2,
                 const float* __restrict__ b2,
                 float* __restrict__ out)
{
    // 2 buffers x 32 chunks x 512 bf16; chunk c = kc*4 + jsub, kc in [0,8)
    __shared__ __align__(16) unsigned short ldsB[32768];   // 64 KB

    const int t    = threadIdx.x;
    const int w    = t >> 6;        // wave 0..3
    const int lane = t & 63;
    const int r16  = lane & 15;
    const int quad = lane >> 4;

    const int e_base = blockIdx.x * 256 + w * 64;
    int sb[4], db[4];
#pragma unroll
    for (int mt = 0; mt < 4; ++mt) {
        int e = min(e_base + mt * 16 + r16, NE - 1);
        sb[mt] = ei[e] << 8;                  // byte base, 256 B per node row
        db[mt] = ei[NE + e] << 8;
    }

    const char* eb = (const char*)embb;

    float attP[4][4];
#pragma unroll
    for (int mt = 0; mt < 4; ++mt)
#pragma unroll
        for (int rg = 0; rg < 4; ++rg) attP[mt][rg] = 0.0f;

    // stage segment jo into buffer buf: wave w stages chunks w*8..w*8+7
#define STAGE(jo_, buf_)                                                     \
    {                                                                        \
        _Pragma("unroll")                                                    \
        for (int cc = 0; cc < 8; ++cc) {                                     \
            int c    = w * 8 + cc;                                           \
            int kc   = c >> 2;                                               \
            int jsub = c & 3;                                                \
            int g    = (kc * 8 + (jo_)) * 4 + jsub;                          \
            GLOAD_LDS16(w1p + g * 512 + lane * 8,                            \
                        ldsB + (buf_) * 16384 + c * 512);                    \
        }                                                                    \
    }

    STAGE(0, 0);
    __syncthreads();

    for (int jo = 0; jo < 8; ++jo) {
        const int cur = jo & 1;
        if (jo < 7) STAGE(jo + 1, cur ^ 1);   // prefetch next segment early

        f32x4 acc[4][4];   // [mt][jsub]
#pragma unroll
        for (int mt = 0; mt < 4; ++mt)
#pragma unroll
            for (int js = 0; js < 4; ++js) acc[mt][js] = f32x4{};

#pragma unroll
        for (int kc = 0; kc < 8; ++kc) {
            const int off = (kc & 3) * 64 + quad * 16;   // bytes in half-row
            short8 A[4];
#pragma unroll
            for (int mt = 0; mt < 4; ++mt)
                A[mt] = *(const short8*)(eb + ((kc >= 4) ? db[mt] : sb[mt]) + off);
#pragma unroll
            for (int jsub = 0; jsub < 4; ++jsub) {
                short8 B = *(const short8*)(ldsB + cur * 16384 +
                                            (kc * 4 + jsub) * 512 + lane * 8);
#pragma unroll
                for (int mt = 0; mt < 4; ++mt)
                    acc[mt][jsub] = MFMA16(A[mt], B, acc[mt][jsub]);
            }
        }

        // epilogue: h = relu(y + b1[j]); attP += h * W2[j]   (j col = r16)
#pragma unroll
        for (int jsub = 0; jsub < 4; ++jsub) {
            const int j = jo * 64 + jsub * 16 + r16;
            const float b1v = b1[j], w2v = W2[j];
#pragma unroll
            for (int mt = 0; mt < 4; ++mt)
#pragma unroll
                for (int rg = 0; rg < 4; ++rg)
                    attP[mt][rg] += fmaxf(acc[mt][jsub][rg] + b1v, 0.0f) * w2v;
        }
        __syncthreads();   // prefetch landed + all reads of cur done
    }
#undef STAGE

    // sum over the 16 j-columns: butterfly over low 4 lane bits
#pragma unroll
    for (int mt = 0; mt < 4; ++mt)
#pragma unroll
        for (int rg = 0; rg < 4; ++rg) {
            float v = attP[mt][rg];
#pragma unroll
            for (int msk = 1; msk <= 8; msk <<= 1) v += __shfl_xor(v, msk, 64);
            attP[mt][rg] = v;
        }

    const float bias2 = b2[0];
    if (r16 < 4) {
#pragma unroll
        for (int mt = 0; mt < 4; ++mt) {
            const int row = quad * 4 + r16;    // C/D row = (lane>>4)*4 + reg
            const int e   = e_base + mt * 16 + row;
            if (e < NE) out[O_ATT + e] = attP[mt][r16] + bias2;
        }
    }
}

// ---------------- per-graph top-k screening ----------------
__device__ __forceinline__ unsigned enc_key(float f) {
    unsigned u = __float_as_uint(f);
    return (u & 0x80000000u) ? ~u : (u | 0x80000000u);
}
__device__ __forceinline__ float dec_key(unsigned k) {
    unsigned u = (k & 0x80000000u) ? (k ^ 0x80000000u) : ~k;
    return __uint_as_float(u);
}

__global__ __launch_bounds__(256)
void topk4_kernel(const int* __restrict__ ei, float* __restrict__ out,
                  float* __restrict__ deg, int* __restrict__ bcnt,
                  int* __restrict__ need, int* __restrict__ blist)
{
    __shared__ int cnt;

    const int g  = blockIdx.x;
    const int t  = threadIdx.x;
    const int e0 = g * EPG;
    const int cbase = t * 16;            // blocked chunk, threads 0..249 active
    const bool act = (t < 250);

    // keys live in registers: 16 per thread, loaded as 4 x float4
    unsigned kreg[16];
    if (act) {
#pragma unroll
        for (int q4 = 0; q4 < 4; ++q4) {
            float4 v = *(const float4*)&out[O_ATT + e0 + cbase + q4 * 4];
            kreg[q4 * 4 + 0] = enc_key(v.x);
            kreg[q4 * 4 + 1] = enc_key(v.y);
            kreg[q4 * 4 + 2] = enc_key(v.z);
            kreg[q4 * 4 + 3] = enc_key(v.w);
        }
    }

    // binary search for K = max T with count(key >= T) >= KSEL
    unsigned lo = 0u, hi = 0xFFFFFFFFu;
    while (lo < hi) {
        unsigned mid = lo + ((hi - lo) >> 1) + 1u;
        if (t == 0) cnt = 0;
        __syncthreads();
        int c = 0;
        if (act) {
#pragma unroll
            for (int q = 0; q < 16; ++q) c += (kreg[q] >= mid) ? 1 : 0;
        }
        if (c) atomicAdd(&cnt, c);
        __syncthreads();
        int f = cnt;
        if (f >= KSEL) lo = mid; else hi = mid - 1u;
        __syncthreads();
    }
    const unsigned K = lo;
    const float v = dec_key(K);
    const unsigned khi = enc_key(v + DELTA);
    const unsigned klo = enc_key(v - DELTA);

    // in_cnt = #{key > khi}
    if (t == 0) cnt = 0;
    __syncthreads();
    {
        int c = 0;
        if (act) {
#pragma unroll
            for (int q = 0; q < 16; ++q) c += (kreg[q] > khi) ? 1 : 0;
        }
        if (c) atomicAdd(&cnt, c);
    }
    __syncthreads();
    if (t == 0) need[g] = KSEL - cnt;

    // classify own chunk; boundary edges deferred to blist
    if (act) {
#pragma unroll
        for (int q = 0; q < 16; ++q) {
            unsigned kk = kreg[q];
            int ge = e0 + cbase + q;
            float a = dec_key(kk);
            if (kk > khi) {
                out[O_CEW + ge]  = a;
                out[O_SEW + ge]  = 0.0f;
                out[O_MASK + ge] = 1.0f;
                atomicAdd(&deg[ei[ge]], 1.0f);
                atomicAdd(&deg[ei[NE + ge]], 1.0f);
            } else if (kk < klo) {
                out[O_CEW + ge]  = 0.0f;
                out[O_SEW + ge]  = a;
                out[O_MASK + ge] = 0.0f;
            } else {
                int p = atomicAdd(&bcnt[g], 1);
                if (p < MAXB) blist[g * MAXB + p] = ge;
            }
        }
    }
}

// ---------------- exact fp32 recompute of boundary edges ----------------
// j-split variant of the round-1 fp32 MLP.
// Block index remap (occupancy!): blk = ch*(NG*RJT) + g*RJT + jt so the
// active blocks (ch small, bc ~140 -> ch<2) are CONTIGUOUS indices 0..1599
// and spread across all 256 CUs; the old g-major order piled all active
// blocks onto ~64 CUs (OccupancyPercent 18.8, dur 184 us).
#define TE_  128
#define PADX 132
#define PADW 68

__global__ __launch_bounds__(256)
void repair_kernel(const float* __restrict__ emb, const int* __restrict__ ei,
                   const float* __restrict__ W1, const float* __restrict__ b1,
                   const float* __restrict__ W2,
                   const int* __restrict__ bcnt, const int* __restrict__ blist,
                   float* __restrict__ attx8)
{
    const int blk = blockIdx.x;
    const int ch  = blk / (NG * RJT);          // 0..NRC-1
    const int rem = blk - ch * (NG * RJT);
    const int g   = rem >> 3;                  // /RJT
    const int jt  = rem & 7;
    const int bc  = min(bcnt[g], MAXB);
    if (ch * 128 >= bc) return;

    __shared__ __align__(16) float Xs[32 * PADX];   // 16.9 KB
    __shared__ __align__(16) float Ws[32 * PADW];   //  8.7 KB
    __shared__ int sidx[TE_], cidx[TE_];

    const int t = threadIdx.x;
    if (t < TE_) {
        int lid = ch * 128 + t;
        int lc  = min(lid, bc - 1);
        int e   = blist[g * MAXB + lc];
        sidx[t] = ei[e];
        cidx[t] = ei[NE + e];
    }
    __syncthreads();

    const int te = t & 15;     // edge group: edges te*8..te*8+7
    const int tj = t >> 4;     // j group: j jt*64 + tj*4..+3

    float acc[8][4];
#pragma unroll
    for (int a = 0; a < 8; ++a)
#pragma unroll
        for (int b = 0; b < 4; ++b) acc[a][b] = 0.0f;

    for (int kt = 0; kt < 8; ++kt) {
        __syncthreads();
        // stage X: 32 k x 128 e (gathered), float4 along k
#pragma unroll
        for (int i = 0; i < 4; ++i) {
            int flat = i * 256 + t;           // 0..1023
            int e  = flat >> 3;
            int k4 = flat & 7;
            int k  = kt * 32 + k4 * 4;
            const float* src;
            if (k < HID) src = emb + (long)sidx[e] * HID + k;
            else         src = emb + (long)cidx[e] * HID + (k - HID);
            float4 v = *(const float4*)src;
            int kl = k4 * 4;
            Xs[(kl + 0) * PADX + e] = v.x;
            Xs[(kl + 1) * PADX + e] = v.y;
            Xs[(kl + 2) * PADX + e] = v.z;
            Xs[(kl + 3) * PADX + e] = v.w;
        }
        // stage W1 tile: 32 k x 64 j (this block's jt slice)
#pragma unroll
        for (int i = 0; i < 2; ++i) {
            int flat = i * 256 + t;           // 0..511
            int kl = flat >> 4;
            int j4 = flat & 15;
            float4 v = *(const float4*)&W1[(kt * 32 + kl) * 512 + jt * 64 + j4 * 4];
            *(float4*)&Ws[kl * PADW + j4 * 4] = v;
        }
        __syncthreads();

#pragma unroll 4
        for (int kl = 0; kl < 32; ++kl) {
            float4 xa = *(const float4*)&Xs[kl * PADX + te * 8];
            float4 xb = *(const float4*)&Xs[kl * PADX + te * 8 + 4];
            float4 wa = *(const float4*)&Ws[kl * PADW + tj * 4];
            float xv[8] = {xa.x, xa.y, xa.z, xa.w, xb.x, xb.y, xb.z, xb.w};
            float wv[4] = {wa.x, wa.y, wa.z, wa.w};
#pragma unroll
            for (int a = 0; a < 8; ++a)
#pragma unroll
                for (int b = 0; b < 4; ++b)
                    acc[a][b] = fmaf(xv[a], wv[b], acc[a][b]);
        }
    }

    // epilogue: relu(+b1) * W2 over this block's 4 j's per thread
    const int jb = jt * 64 + tj * 4;
    float4 b1a = *(const float4*)&b1[jb];
    float4 w2a = *(const float4*)&W2[jb];
    float bv[4] = {b1a.x, b1a.y, b1a.z, b1a.w};
    float wv[4] = {w2a.x, w2a.y, w2a.z, w2a.w};
    float attp[8];
#pragma unroll
    for (int a = 0; a < 8; ++a) {
        float s = 0.0f;
#pragma unroll
        for (int b = 0; b < 4; ++b)
            s = fmaf(fmaxf(acc[a][b] + bv[b], 0.0f), wv[b], s);
        attp[a] = s;
    }

    // reduce across the 16 tj groups
    __syncthreads();
    float* red = Xs;   // 16*136 = 2176 floats, fits
#pragma unroll
    for (int a = 0; a < 8; ++a) red[tj * 136 + te * 8 + a] = attp[a];
    __syncthreads();
    if (t < TE_ && ch * 128 + t < bc) {
        float s = 0.0f;
#pragma unroll
        for (int q = 0; q < 16; ++q) s += red[q * 136 + t];
        attx8[(g * MAXB + ch * 128 + t) * RJT + jt] = s;
    }
}

// ---------------- exact selection among boundary edges ----------------
__global__ __launch_bounds__(256)
void select_kernel(const int* __restrict__ ei, const int* __restrict__ bcnt,
                   const int* __restrict__ need, const int* __restrict__ blist,
                   const float* __restrict__ attx8, const float* __restrict__ b2,
                   float* __restrict__ out, float* __restrict__ deg)
{
    __shared__ float sa[MAXB];
    __shared__ int   si[MAXB];
    const int g = blockIdx.x;
    const int t = threadIdx.x;
    const int b = min(bcnt[g], MAXB);
    const int n = need[g];
    const float bias2 = b2[0];

    for (int i = t; i < b; i += 256) {
        float s = bias2;
#pragma unroll
        for (int jt = 0; jt < RJT; ++jt)
            s += attx8[(g * MAXB + i) * RJT + jt];
        sa[i] = s;
        si[i] = blist[g * MAXB + i];
    }
    __syncthreads();

    for (int i = t; i < b; i += 256) {
        float ai = sa[i];
        int   ii = si[i];
        int rank = 0;
        for (int j = 0; j < b; ++j)
            rank += (sa[j] > ai || (sa[j] == ai && si[j] < ii)) ? 1 : 0;
        bool flag = rank < n;
        out[O_CEW + ii]  = flag ? ai : 0.0f;
        out[O_SEW + ii]  = flag ? 0.0f : ai;
        out[O_MASK + ii] = flag ? 1.0f : 0.0f;
        if (flag) {
            atomicAdd(&deg[ei[ii]], 1.0f);
            atomicAdd(&deg[ei[NE + ii]], 1.0f);
        }
    }
}

// ---------------- node relabel: global prefix scan over node_mask ----------------
__global__ __launch_bounds__(256)
void scanA(const float* __restrict__ deg, int* __restrict__ partials)
{
    __shared__ int s[256];
    int t = threadIdx.x;
    int n = blockIdx.x * 256 + t;
    int m = (n < NNODES && deg[n] > 0.5f) ? 1 : 0;
    s[t] = m;
    __syncthreads();
    for (int off = 128; off > 0; off >>= 1) {
        if (t < off) s[t] += s[t + off];
        __syncthreads();
    }
    if (t == 0) partials[blockIdx.x] = s[0];
}

__global__ __launch_bounds__(256)
void scanB(int* __restrict__ partials)
{
    __shared__ int s[256];
    int t = threadIdx.x;
    int v = (t < NB_SCAN) ? partials[t] : 0;
    s[t] = v;
    __syncthreads();
    for (int off = 1; off < 256; off <<= 1) {
        int x = (t >= off) ? s[t - off] : 0;
        __syncthreads();
        s[t] += x;
        __syncthreads();
    }
    if (t < NB_SCAN) partials[t] = s[t] - v;   // exclusive prefix
}

__global__ __launch_bounds__(256)
void scanC(float* __restrict__ deg_nm, const int* __restrict__ partials,
           int* __restrict__ newid)
{
    __shared__ int s[256];
    int t = threadIdx.x;
    int b = blockIdx.x;
    int n = b * 256 + t;
    int m = (n < NNODES && deg_nm[n] > 0.5f) ? 1 : 0;
    s[t] = m;
    __syncthreads();
    for (int off = 1; off < 256; off <<= 1) {
        int x = (t >= off) ? s[t - off] : 0;
        __syncthreads();
        s[t] += x;
        __syncthreads();
    }
    if (n < NNODES) {
        newid[n]  = partials[b] + s[t] - 1;   // cumsum(mask)-1
        deg_nm[n] = m ? 1.0f : 0.0f;          // finalize node_mask output
    }
}

// ---------------- fused epilogue: edge relabel + causal_x ----------------
// blocks [0,1563): causal_edge_index; blocks [1563,7813): causal_x float4s
#define FIN_EDGE 1563
#define FIN_GRID (FIN_EDGE + 6250)

__global__ __launch_bounds__(256)
void final_kernel(const float* __restrict__ emb, const int* __restrict__ ei,
                  const int* __restrict__ newid, const float* __restrict__ nm,
                  float* __restrict__ out)
{
    const int blk = blockIdx.x;
    const int t   = threadIdx.x;
    if (blk < FIN_EDGE) {
        int e = blk * 256 + t;
        if (e >= NE) return;
        bool flag = out[O_MASK + e] > 0.5f;
        int row = ei[e];
        int col = ei[NE + e];
        out[O_CEI + e]      = flag ? (float)newid[row] : -1.0f;
        out[O_CEI + NE + e] = flag ? (float)newid[col] : -1.0f;
    } else {
        int i4 = (blk - FIN_EDGE) * 256 + t;           // float4 index
        if (i4 >= NNODES * HID / 4) return;
        int n = i4 >> 5;                               // 32 float4 per node
        float4 v = ((const float4*)emb)[i4];
        if (!(nm[n] > 0.5f)) v = make_float4(0.0f, 0.0f, 0.0f, 0.0f);
        ((float4*)(out + O_CX))[i4] = v;
    }
}

extern "C" void kernel_launch(void* const* d_in, const int* in_sizes, int n_in,
                              void* d_out, int out_size, void* d_ws, size_t ws_size,
                              hipStream_t stream)
{
    const float* emb = (const float*)d_in[0];
    const int*   ei  = (const int*)d_in[1];
    // d_in[2] = node_batch (implied by edge layout; unused)
    const float* W1  = (const float*)d_in[3];
    const float* b1  = (const float*)d_in[4];
    const float* W2  = (const float*)d_in[5];
    const float* b2  = (const float*)d_in[6];
    float* out = (float*)d_out;

    char* wsb = (char*)d_ws;
    int*   newid    = (int*)wsb;                          // 200000 B
    int*   partials = (int*)(wsb + 200704);
    int*   bcnt     = (int*)(wsb + 201728);               // NG ints
    int*   need     = (int*)(wsb + 202752);               // NG ints
    int*   blist    = (int*)(wsb + 203776);               // NG*MAXB ints (400 KB)
    float* attx8    = (float*)(wsb + 203776 + NG*MAXB*4); // NG*MAXB*RJT floats (3.3 MB)
    unsigned short* embb = (unsigned short*)(wsb + 203776 + NG*MAXB*4 + NG*MAXB*RJT*4);
    unsigned short* w1p  = embb + NNODES * HID;           // 131072 bf16
    float* deg = out + O_NMASK;                           // node_mask region as deg accum

    prep_kernel<<<PREP_GRID, 256, 0, stream>>>(emb, W1, embb, w1p, deg, bcnt);
    att5_kernel<<<(NE + 255) / 256, 256, 0, stream>>>(embb, w1p, ei, b1, W2, b2, out);
    topk4_kernel<<<NG, 256, 0, stream>>>(ei, out, deg, bcnt, need, blist);
    repair_kernel<<<NG * NRC * RJT, 256, 0, stream>>>(emb, ei, W1, b1, W2,
                                                      bcnt, blist, attx8);
    select_kernel<<<NG, 256, 0, stream>>>(ei, bcnt, need, blist, attx8, b2, out, deg);
    scanA<<<NB_SCAN, 256, 0, stream>>>(deg, partials);
    scanB<<<1, 256, 0, stream>>>(partials);
    scanC<<<NB_SCAN, 256, 0, stream>>>(deg, partials, newid);
    final_kernel<<<FIN_GRID, 256, 0, stream>>>(emb, ei, newid, deg, out);
}